// Round 2
// baseline (262.712 us; speedup 1.0000x reference)
//
#include <hip/hip_runtime.h>

// ---------------------------------------------------------------------------
// MultiHeadAttention forward, MI355X/gfx950.
// Pipeline: convert(f32->bf16) -> GEMM Q/K/V proj -> flash attention -> GEMM O proj
// ---------------------------------------------------------------------------

typedef short bf16x8 __attribute__((ext_vector_type(8)));
typedef short bf16x4 __attribute__((ext_vector_type(4)));
typedef float f32x4 __attribute__((ext_vector_type(4)));
typedef int i32x4 __attribute__((ext_vector_type(4)));
typedef unsigned short u16;
typedef unsigned short u16x8 __attribute__((ext_vector_type(8)));
typedef unsigned short u16x4 __attribute__((ext_vector_type(4)));

#define MFMA16(a, b, c) __builtin_amdgcn_mfma_f32_16x16x32_bf16((a), (b), (c), 0, 0, 0)
#define GLD16(gp, lp)                                                     \
  __builtin_amdgcn_global_load_lds(                                       \
      (const __attribute__((address_space(1))) void*)(gp),                \
      (__attribute__((address_space(3))) void*)(lp), 16, 0, 0)

__device__ __forceinline__ f32x4 MFMA_PV(bf16x4 a, bf16x4 b, f32x4 c) {
#if __has_builtin(__builtin_amdgcn_mfma_f32_16x16x16bf16_1k)
  return __builtin_amdgcn_mfma_f32_16x16x16bf16_1k(a, b, c, 0, 0, 0);
#else
  asm("v_mfma_f32_16x16x16_bf16 %0, %1, %2, %0" : "+v"(c) : "v"(a), "v"(b));
  return c;
#endif
}

__device__ __forceinline__ u16 f2bf(float f) {
  union { float f; unsigned u; } v; v.f = f;
  return (u16)((v.u + 0x7fffu + ((v.u >> 16) & 1u)) >> 16);
}
__device__ __forceinline__ unsigned pk2(float x, float y) {
  union { float f; unsigned u; } a, b;
  a.f = x; b.f = y;
  return ((a.u + 0x8000u) >> 16) | ((b.u + 0x8000u) & 0xffff0000u);
}

// ---------------- f32 -> bf16 conversion (7 arrays in one launch) ----------
struct ConvDesc { const float* src; u16* dst; int n; };
struct ConvArgs { ConvDesc d[7]; };

__global__ __launch_bounds__(256) void k_convert(ConvArgs a) {
  ConvDesc cd = a.d[blockIdx.y];
  int i = (blockIdx.x * 256 + threadIdx.x) * 8;
  if (i >= cd.n) return;
  const float4* s = (const float4*)(cd.src + i);
  float4 f0 = s[0], f1 = s[1];
  u16x8 o;
  o[0] = f2bf(f0.x); o[1] = f2bf(f0.y); o[2] = f2bf(f0.z); o[3] = f2bf(f0.w);
  o[4] = f2bf(f1.x); o[5] = f2bf(f1.y); o[6] = f2bf(f1.z); o[7] = f2bf(f1.w);
  *(u16x8*)(cd.dst + i) = o;
}

// ---------------- bf16 GEMM: C[M,N] = A[M,K] * B[N,K]^T + bias ------------
__global__ __launch_bounds__(256, 2)
void k_gemm_bt(const u16* __restrict__ A, const u16* __restrict__ Bw,
               const float* __restrict__ bias, void* __restrict__ outp,
               int mode) {
  __shared__ u16 As[128 * 32];
  __shared__ u16 Bs[128 * 32];
  const int tid = threadIdx.x;
  const int lane = tid & 63;
  const int wv = tid >> 6;
  const int wr = wv >> 1, wc = wv & 1;
  const int m0 = blockIdx.y * 128, n0 = blockIdx.x * 128;

  f32x4 acc[4][4] = {};

  const int s0 = tid, s1 = 256 + tid;
  const int r0 = s0 >> 2, c0 = (s0 & 3) ^ (r0 & 3);
  const int r1 = s1 >> 2, c1 = (s1 & 3) ^ (r1 & 3);
  const u16* gA0 = A + (size_t)(m0 + r0) * 1024 + c0 * 8;
  const u16* gA1 = A + (size_t)(m0 + r1) * 1024 + c1 * 8;
  const u16* gB0 = Bw + (size_t)(n0 + r0) * 1024 + c0 * 8;
  const u16* gB1 = Bw + (size_t)(n0 + r1) * 1024 + c1 * 8;
  u16* lA0 = As + (tid & ~63) * 8;
  u16* lA1 = As + (256 + (tid & ~63)) * 8;
  u16* lB0 = Bs + (tid & ~63) * 8;
  u16* lB1 = Bs + (256 + (tid & ~63)) * 8;

  for (int k0 = 0; k0 < 1024; k0 += 32) {
    GLD16(gA0 + k0, lA0);
    GLD16(gA1 + k0, lA1);
    GLD16(gB0 + k0, lB0);
    GLD16(gB1 + k0, lB1);
    __syncthreads();
    bf16x8 af[4], bfr[4];
#pragma unroll
    for (int mi = 0; mi < 4; mi++) {
      int row = wr * 64 + mi * 16 + (lane & 15);
      int byt = row * 64 + (((lane >> 4) * 16) ^ ((row & 3) << 4));
      af[mi] = *(const bf16x8*)((const char*)As + byt);
    }
#pragma unroll
    for (int ni = 0; ni < 4; ni++) {
      int row = wc * 64 + ni * 16 + (lane & 15);
      int byt = row * 64 + (((lane >> 4) * 16) ^ ((row & 3) << 4));
      bfr[ni] = *(const bf16x8*)((const char*)Bs + byt);
    }
#pragma unroll
    for (int mi = 0; mi < 4; mi++)
#pragma unroll
      for (int ni = 0; ni < 4; ni++)
        acc[mi][ni] = MFMA16(af[mi], bfr[ni], acc[mi][ni]);
    __syncthreads();
  }

#pragma unroll
  for (int ni = 0; ni < 4; ni++) {
    int n = n0 + wc * 64 + ni * 16 + (lane & 15);
    float bv = bias[n];
#pragma unroll
    for (int mi = 0; mi < 4; mi++) {
      int mb = m0 + wr * 64 + mi * 16 + (lane >> 4) * 4;
      if (mode == 2) {
        float* O = (float*)outp;
#pragma unroll
        for (int r = 0; r < 4; r++)
          O[(size_t)(mb + r) * 1024 + n] = acc[mi][ni][r] + bv;
      } else if (mode == 0) {
        u16* O = (u16*)outp;
        int b = mb >> 11, q = mb & 2047;
        int h = n >> 6, dk = n & 63;
        size_t base = ((size_t)(b * 16 + h) * 2048 + q) * 64 + dk;
#pragma unroll
        for (int r = 0; r < 4; r++)
          O[base + (size_t)r * 64] = f2bf(acc[mi][ni][r] + bv);
      } else {  // mode 1: V^T [B,H,64,NK]
        u16* O = (u16*)outp;
        int b = mb >> 11, kv = mb & 2047;
        int h = n >> 6, dk = n & 63;
        u16x4 pk;
#pragma unroll
        for (int r = 0; r < 4; r++) pk[r] = f2bf(acc[mi][ni][r] + bv);
        *(u16x4*)((u16*)O + ((size_t)((b * 16 + h) * 64 + dk)) * 2048 + kv) = pk;
      }
    }
  }
}

// ---------------- flash attention (swapped-QK^T, in-register P) -----------
// grid (h=16, qt=32, b=2), 256 threads = 4 waves, wave w owns q rows w*16..+15.
// Each lane owns ONE q row (q = lane&15) and 16 kv per tile. P fragments feed
// PV's mfma_16x16x16 A-operand directly (no LDS round trip). K/V double-
// buffered via global_load_lds with XOR-swizzled source; bias reg-prefetched.
__global__ __launch_bounds__(256, 2)
void k_attn(const u16* __restrict__ Qb, const u16* __restrict__ Kb,
            const u16* __restrict__ Vt, const float* __restrict__ bias,
            const int* __restrict__ mask, u16* __restrict__ Ob) {
  __shared__ u16 Ks[2][64 * 64];
  __shared__ u16 Vs[2][64 * 64];

  const int tid = threadIdx.x, lane = tid & 63, w = tid >> 6;
  const int g = lane >> 4, q = lane & 15;
  const int h = blockIdx.x, qt = blockIdx.y, b = blockIdx.z;
  const int q0 = qt * 64;
  const size_t bh = (size_t)(b * 16 + h);

  // Q as B-operand: col q = lane&15, k(d) = g*8 + ch*32
  const u16* Qrow = Qb + (bh * 2048 + q0 + w * 16 + q) * 64;
  bf16x8 bq[2];
  bq[0] = *(const bf16x8*)(Qrow + g * 8);
  bq[1] = *(const bf16x8*)(Qrow + 32 + g * 8);

  f32x4 acc[4] = {};          // O[q=4g+j][d=dblk*16+q], per dblk
  float mrun = -1e30f, lrun = 0.f;

  // staging map: slot s -> row s>>3, chunk (s&7)^(row&7) (pre-swizzled source)
  const int sA = tid, sB = tid + 256;
  const int r0 = sA >> 3, c0 = (sA & 7) ^ (r0 & 7);
  const int r1 = sB >> 3, c1 = (sB & 7) ^ (r1 & 7);
  const u16* Kg = Kb + bh * 2048 * 64;
  const u16* Vg = Vt + bh * 64 * 2048;
  const int ld0 = (tid & ~63) * 8, ld1 = ld0 + 2048;

  const float* brow = bias + ((size_t)b * 2048 + q0 + w * 16 + q) * 2048;
  const int* mrow = mask + b * 2048;

  // prologue: stage tile 0 + prefetch bias tile 0
  GLD16(Kg + (size_t)r0 * 64 + c0 * 8, &Ks[0][ld0]);
  GLD16(Kg + (size_t)r1 * 64 + c1 * 8, &Ks[0][ld1]);
  GLD16(Vg + (size_t)r0 * 2048 + c0 * 8, &Vs[0][ld0]);
  GLD16(Vg + (size_t)r1 * 2048 + c1 * 8, &Vs[0][ld1]);
  f32x4 bpf[4];
#pragma unroll
  for (int c = 0; c < 4; c++)
    bpf[c] = *(const f32x4*)(brow + c * 16 + g * 4);
  __syncthreads();

  int buf = 0;
  for (int t = 0; t < 32; t++) {
    const int kv0 = t * 64;
    f32x4 bv[4];
    i32x4 mv[4];
#pragma unroll
    for (int c = 0; c < 4; c++) bv[c] = bpf[c];
#pragma unroll
    for (int c = 0; c < 4; c++)
      mv[c] = *(const i32x4*)(mrow + kv0 + c * 16 + g * 4);

    if (t < 31) {  // stage next tile + prefetch next bias
      const int nkv = kv0 + 64, nb = buf ^ 1;
      GLD16(Kg + (size_t)(nkv + r0) * 64 + c0 * 8, &Ks[nb][ld0]);
      GLD16(Kg + (size_t)(nkv + r1) * 64 + c1 * 8, &Ks[nb][ld1]);
      GLD16(Vg + (size_t)r0 * 2048 + nkv + c0 * 8, &Vs[nb][ld0]);
      GLD16(Vg + (size_t)r1 * 2048 + nkv + c1 * 8, &Vs[nb][ld1]);
#pragma unroll
      for (int c = 0; c < 4; c++)
        bpf[c] = *(const f32x4*)(brow + nkv + c * 16 + g * 4);
    }

    // S^T = K * Q^T : D col = q (lane&15), row = kv_local = 4g+r
    f32x4 sc[4];
    __builtin_amdgcn_s_setprio(1);
#pragma unroll
    for (int c = 0; c < 4; c++) {
      const int kvr = c * 16 + q;
      f32x4 z = {};
#pragma unroll
      for (int ch = 0; ch < 2; ch++) {
        bf16x8 ak = *(const bf16x8*)((const char*)&Ks[buf][0] + kvr * 128 +
                                     ((ch * 64 + g * 16) ^ ((kvr & 7) << 4)));
        z = MFMA16(ak, bq[ch], z);
      }
      sc[c] = z;
    }
    __builtin_amdgcn_s_setprio(0);

    // softmax: each lane = one q row, 16 kv values
    float p[4][4];
    float tmax = -1e30f;
#pragma unroll
    for (int c = 0; c < 4; c++) {
#pragma unroll
      for (int r = 0; r < 4; r++) {
        float s = fmaf(sc[c][r], 0.125f, bv[c][r]);
        s = (mv[c][r] == 0) ? -1e9f : s;
        p[c][r] = s;
        tmax = fmaxf(tmax, s);
      }
    }
    tmax = fmaxf(tmax, __shfl_xor(tmax, 16, 64));
    tmax = fmaxf(tmax, __shfl_xor(tmax, 32, 64));
    float mnew = fmaxf(mrun, tmax);
    float alpha = __expf(mrun - mnew);
    mrun = mnew;

    float rsum = 0.f;
#pragma unroll
    for (int c = 0; c < 4; c++)
#pragma unroll
      for (int r = 0; r < 4; r++) {
        p[c][r] = __expf(p[c][r] - mnew);
        rsum += p[c][r];
      }
    rsum += __shfl_xor(rsum, 16, 64);
    rsum += __shfl_xor(rsum, 32, 64);
    lrun = lrun * alpha + rsum;

    // rescale O: acc rows are q' = 4g+j; alpha lives at lane q'
    float aO[4];
#pragma unroll
    for (int j = 0; j < 4; j++) aO[j] = __shfl(alpha, g * 4 + j, 64);
#pragma unroll
    for (int d = 0; d < 4; d++)
#pragma unroll
      for (int j = 0; j < 4; j++) acc[d][j] *= aO[j];

    // PV: P frag (in-register) is the A-operand of mfma_16x16x16
    __builtin_amdgcn_s_setprio(1);
#pragma unroll
    for (int c = 0; c < 4; c++) {
      union { unsigned u[2]; bf16x4 v; } pa;
      pa.u[0] = pk2(p[c][0], p[c][1]);
      pa.u[1] = pk2(p[c][2], p[c][3]);
#pragma unroll
      for (int d = 0; d < 4; d++) {
        const int dr = d * 16 + q;
        bf16x4 vb = *(const bf16x4*)((const char*)&Vs[buf][0] + dr * 128 +
                                     ((c * 32 + g * 8) ^ ((dr & 7) << 4)));
        acc[d] = MFMA_PV(pa.v, vb, acc[d]);
      }
    }
    __builtin_amdgcn_s_setprio(0);

    __syncthreads();
    buf ^= 1;
  }

  // epilogue: O[q'=4g+j][d], divide by l[q'] (bpermute), write bf16
  float linv = 1.0f / lrun;
#pragma unroll
  for (int j = 0; j < 4; j++) {
    float li = __shfl(linv, g * 4 + j, 64);
    int qq = q0 + w * 16 + g * 4 + j;
#pragma unroll
    for (int d = 0; d < 4; d++)
      Ob[((size_t)b * 2048 + qq) * 1024 + h * 64 + d * 16 + q] =
          f2bf(acc[d][j] * li);
  }
}

// ---------------------------------------------------------------------------
extern "C" void kernel_launch(void* const* d_in, const int* in_sizes, int n_in,
                              void* d_out, int out_size, void* d_ws,
                              size_t ws_size, hipStream_t stream) {
  (void)in_sizes; (void)n_in; (void)out_size; (void)ws_size;
  const float* q_in = (const float*)d_in[0];
  const float* k_in = (const float*)d_in[1];
  const float* v_in = (const float*)d_in[2];
  const int* mask = (const int*)d_in[3];
  const float* attn_bias = (const float*)d_in[4];
  const float* w_q = (const float*)d_in[5];
  const float* b_q = (const float*)d_in[6];
  const float* w_k = (const float*)d_in[7];
  const float* b_k = (const float*)d_in[8];
  const float* w_v = (const float*)d_in[9];
  const float* b_v = (const float*)d_in[10];
  const float* w_o = (const float*)d_in[11];
  const float* b_o = (const float*)d_in[12];

  const size_t MB = 1u << 20;
  char* ws = (char*)d_ws;
  u16* XQ = (u16*)(ws + 0 * MB);
  u16* XK = (u16*)(ws + 8 * MB);
  u16* XV = (u16*)(ws + 16 * MB);
  u16* WQ = (u16*)(ws + 24 * MB);
  u16* WK = (u16*)(ws + 26 * MB);
  u16* WV = (u16*)(ws + 28 * MB);
  u16* WO = (u16*)(ws + 30 * MB);
  u16* Qb = (u16*)(ws + 32 * MB);
  u16* Kb = (u16*)(ws + 40 * MB);
  u16* Vt = (u16*)(ws + 48 * MB);
  u16* Ob = (u16*)(ws + 56 * MB);

  ConvArgs ca;
  ca.d[0] = {q_in, XQ, 4096 * 1024};
  ca.d[1] = {k_in, XK, 4096 * 1024};
  ca.d[2] = {v_in, XV, 4096 * 1024};
  ca.d[3] = {w_q, WQ, 1024 * 1024};
  ca.d[4] = {w_k, WK, 1024 * 1024};
  ca.d[5] = {w_v, WV, 1024 * 1024};
  ca.d[6] = {w_o, WO, 1024 * 1024};
  k_convert<<<dim3(2048, 7), 256, 0, stream>>>(ca);

  dim3 ggrid(8, 32);  // N/128, M/128
  k_gemm_bt<<<ggrid, 256, 0, stream>>>(XQ, WQ, b_q, (void*)Qb, 0);
  k_gemm_bt<<<ggrid, 256, 0, stream>>>(XK, WK, b_k, (void*)Kb, 0);
  k_gemm_bt<<<ggrid, 256, 0, stream>>>(XV, WV, b_v, (void*)Vt, 1);

  k_attn<<<dim3(16, 32, 2), 256, 0, stream>>>(Qb, Kb, Vt, attn_bias, mask, Ob);

  k_gemm_bt<<<ggrid, 256, 0, stream>>>(Ob, WO, b_o, d_out, 2);
}

// Round 3
// 206.066 us; speedup vs baseline: 1.2749x; 1.2749x over previous
//
#include <hip/hip_runtime.h>

// ---------------------------------------------------------------------------
// MultiHeadAttention forward, MI355X/gfx950.
// convert(f32->bf16) -> GEMM Q/K/V proj -> biasprep -> flash attention -> GEMM O
// Round 3: counted-vmcnt 2-phase pipelines (no vmcnt(0) drains in loops),
// premasked/prescaled bf16 bias in exp2 domain, fewer softmax VALU ops.
// ---------------------------------------------------------------------------

typedef short bf16x8 __attribute__((ext_vector_type(8)));
typedef short bf16x4 __attribute__((ext_vector_type(4)));
typedef float f32x4 __attribute__((ext_vector_type(4)));
typedef int i32x4 __attribute__((ext_vector_type(4)));
typedef unsigned short u16;
typedef unsigned short u16x8 __attribute__((ext_vector_type(8)));
typedef unsigned short u16x4 __attribute__((ext_vector_type(4)));

#define MFMA16(a, b, c) __builtin_amdgcn_mfma_f32_16x16x32_bf16((a), (b), (c), 0, 0, 0)
#define GLD16(gp, lp)                                                     \
  __builtin_amdgcn_global_load_lds(                                       \
      (const __attribute__((address_space(1))) void*)(gp),                \
      (__attribute__((address_space(3))) void*)(lp), 16, 0, 0)

// counted-vmcnt wait fused with raw barrier (memory clobber pins ordering)
#define WAITVM_BAR(N) asm volatile("s_waitcnt vmcnt(" #N ")\ns_barrier" ::: "memory")
#define BAR() asm volatile("s_barrier" ::: "memory")

#if __has_builtin(__builtin_amdgcn_exp2f)
#define EXP2(x) __builtin_amdgcn_exp2f(x)
#else
#define EXP2(x) exp2f(x)
#endif

__device__ __forceinline__ f32x4 MFMA_PV(bf16x4 a, bf16x4 b, f32x4 c) {
#if __has_builtin(__builtin_amdgcn_mfma_f32_16x16x16bf16_1k)
  return __builtin_amdgcn_mfma_f32_16x16x16bf16_1k(a, b, c, 0, 0, 0);
#else
  asm("v_mfma_f32_16x16x16_bf16 %0, %1, %2, %0" : "+v"(c) : "v"(a), "v"(b));
  return c;
#endif
}

__device__ __forceinline__ u16 f2bf(float f) {
  union { float f; unsigned u; } v; v.f = f;
  return (u16)((v.u + 0x7fffu + ((v.u >> 16) & 1u)) >> 16);
}
__device__ __forceinline__ unsigned pk2(float x, float y) {
  union { float f; unsigned u; } a, b;
  a.f = x; b.f = y;
  return ((a.u + 0x8000u) >> 16) | ((b.u + 0x8000u) & 0xffff0000u);
}

// ---------------- f32 -> bf16 conversion (7 arrays in one launch) ----------
struct ConvDesc { const float* src; u16* dst; int n; };
struct ConvArgs { ConvDesc d[7]; };

__global__ __launch_bounds__(256) void k_convert(ConvArgs a) {
  ConvDesc cd = a.d[blockIdx.y];
  int i = (blockIdx.x * 256 + threadIdx.x) * 8;
  if (i >= cd.n) return;
  const float4* s = (const float4*)(cd.src + i);
  float4 f0 = s[0], f1 = s[1];
  u16x8 o;
  o[0] = f2bf(f0.x); o[1] = f2bf(f0.y); o[2] = f2bf(f0.z); o[3] = f2bf(f0.w);
  o[4] = f2bf(f1.x); o[5] = f2bf(f1.y); o[6] = f2bf(f1.z); o[7] = f2bf(f1.w);
  *(u16x8*)(cd.dst + i) = o;
}

// ---------------- bias preprocessing --------------------------------------
// bias_eff[b][q][perm(kv)] = mask[b][kv] ? bias[b][q][kv]*log2e : -inf (bf16)
// perm within each 64-block: dst g*16 + c*4 + j  <-  src c*16 + g*4 + j
// so each attn lane reads its 16 values as 2 contiguous bf16x8.
__global__ __launch_bounds__(256)
void k_biasprep(const float* __restrict__ bias, const int* __restrict__ mask,
                u16* __restrict__ out) {
  const int i = blockIdx.x * 256 + threadIdx.x;  // 524288 threads, 16 elems each
  const int o0 = i * 16;
  const int rowg = o0 >> 11;       // global row (b*2048+q), 0..4095
  const int b = rowg >> 11;        // 0..1
  const int off = o0 & 2047;
  const int a = off >> 6, g = (off >> 4) & 3;
  const float* src = bias + (size_t)rowg * 2048 + a * 64 + g * 4;
  const int* msk = mask + b * 2048 + a * 64 + g * 4;
  u16x8 w0 = {}, w1 = {};
#pragma unroll
  for (int c = 0; c < 4; c++) {
    f32x4 v = *(const f32x4*)(src + c * 16);
    i32x4 m = *(const i32x4*)(msk + c * 16);
#pragma unroll
    for (int j = 0; j < 4; j++) {
      u16 val = (m[j] != 0) ? f2bf(v[j] * 1.44269504f) : (u16)0xFF80;  // -inf
      if (c < 2) w0[c * 4 + j] = val;
      else       w1[(c - 2) * 4 + j] = val;
    }
  }
  *(u16x8*)(out + o0) = w0;
  *(u16x8*)(out + o0 + 8) = w1;
}

// ---------------- bf16 GEMM: C[M,N] = (A[M,K] * B[N,K]^T + bias)*oscale ---
// counted-vmcnt double-buffered 2-phase loop.
__global__ __launch_bounds__(256, 2)
void k_gemm_bt(const u16* __restrict__ A, const u16* __restrict__ Bw,
               const float* __restrict__ bias, void* __restrict__ outp,
               int mode, float oscale) {
  __shared__ u16 As[2][128 * 32];
  __shared__ u16 Bs[2][128 * 32];
  const int tid = threadIdx.x;
  const int lane = tid & 63;
  const int wv = tid >> 6;
  const int wr = wv >> 1, wc = wv & 1;
  const int m0 = blockIdx.y * 128, n0 = blockIdx.x * 128;

  f32x4 acc[4][4] = {};

  const int s0 = tid, s1 = 256 + tid;
  const int r0 = s0 >> 2, c0 = (s0 & 3) ^ (r0 & 3);
  const int r1 = s1 >> 2, c1 = (s1 & 3) ^ (r1 & 3);
  const u16* gA0 = A + (size_t)(m0 + r0) * 1024 + c0 * 8;
  const u16* gA1 = A + (size_t)(m0 + r1) * 1024 + c1 * 8;
  const u16* gB0 = Bw + (size_t)(n0 + r0) * 1024 + c0 * 8;
  const u16* gB1 = Bw + (size_t)(n0 + r1) * 1024 + c1 * 8;
  u16* lA0 = &As[0][(tid & ~63) * 8];
  u16* lA1 = lA0 + 2048;
  u16* lB0 = &Bs[0][(tid & ~63) * 8];
  u16* lB1 = lB0 + 2048;

  // prologue: stage k=0 into buf0
  GLD16(gA0, lA0); GLD16(gA1, lA1);
  GLD16(gB0, lB0); GLD16(gB1, lB1);
  WAITVM_BAR(0);

#define GEMM_STEP(BUF, K0)                                                  \
  {                                                                         \
    const int nk = ((K0) + 32) & 1023;                                      \
    GLD16(gA0 + nk, lA0 + ((BUF) ^ 1) * 4096);                              \
    GLD16(gA1 + nk, lA1 + ((BUF) ^ 1) * 4096);                              \
    GLD16(gB0 + nk, lB0 + ((BUF) ^ 1) * 4096);                              \
    GLD16(gB1 + nk, lB1 + ((BUF) ^ 1) * 4096);                              \
    WAITVM_BAR(4);                                                          \
    bf16x8 af[4], bfr[4];                                                   \
    _Pragma("unroll")                                                       \
    for (int mi = 0; mi < 4; mi++) {                                        \
      int row = wr * 64 + mi * 16 + (lane & 15);                            \
      int byt = row * 64 + (((lane >> 4) * 16) ^ ((row & 3) << 4));         \
      af[mi] = *(const bf16x8*)((const char*)&As[BUF][0] + byt);            \
    }                                                                       \
    _Pragma("unroll")                                                       \
    for (int ni = 0; ni < 4; ni++) {                                        \
      int row = wc * 64 + ni * 16 + (lane & 15);                            \
      int byt = row * 64 + (((lane >> 4) * 16) ^ ((row & 3) << 4));         \
      bfr[ni] = *(const bf16x8*)((const char*)&Bs[BUF][0] + byt);           \
    }                                                                       \
    __builtin_amdgcn_s_setprio(1);                                          \
    _Pragma("unroll")                                                       \
    for (int mi = 0; mi < 4; mi++)                                          \
      _Pragma("unroll")                                                     \
      for (int ni = 0; ni < 4; ni++)                                        \
        acc[mi][ni] = MFMA16(af[mi], bfr[ni], acc[mi][ni]);                 \
    __builtin_amdgcn_s_setprio(0);                                          \
    BAR();                                                                  \
  }

  for (int k0 = 0; k0 < 1024; k0 += 64) {
    GEMM_STEP(0, k0)
    GEMM_STEP(1, k0 + 32)
  }
#undef GEMM_STEP

#pragma unroll
  for (int ni = 0; ni < 4; ni++) {
    int n = n0 + wc * 64 + ni * 16 + (lane & 15);
    float bv = bias[n];
#pragma unroll
    for (int mi = 0; mi < 4; mi++) {
      int mb = m0 + wr * 64 + mi * 16 + (lane >> 4) * 4;
      if (mode == 2) {
        float* O = (float*)outp;
#pragma unroll
        for (int r = 0; r < 4; r++)
          O[(size_t)(mb + r) * 1024 + n] = (acc[mi][ni][r] + bv) * oscale;
      } else if (mode == 0) {
        u16* O = (u16*)outp;
        int b = mb >> 11, q = mb & 2047;
        int h = n >> 6, dk = n & 63;
        size_t base = ((size_t)(b * 16 + h) * 2048 + q) * 64 + dk;
#pragma unroll
        for (int r = 0; r < 4; r++)
          O[base + (size_t)r * 64] = f2bf((acc[mi][ni][r] + bv) * oscale);
      } else {  // mode 1: V^T [B,H,64,NK]
        u16* O = (u16*)outp;
        int b = mb >> 11, kv = mb & 2047;
        int h = n >> 6, dk = n & 63;
        u16x4 pk;
#pragma unroll
        for (int r = 0; r < 4; r++) pk[r] = f2bf((acc[mi][ni][r] + bv) * oscale);
        *(u16x4*)((u16*)O + ((size_t)((b * 16 + h) * 64 + dk)) * 2048 + kv) = pk;
      }
    }
  }
}

// ---------------- flash attention (counted-vmcnt 2-phase) ------------------
// grid (qt=32, h=16, b=2), 256 threads = 4 waves, wave w owns q rows w*16..+15.
// Swapped QK^T: lane owns one q row; P stays in registers as PV A-operand.
// Bias premasked/prescaled bf16 in exp2 domain, fragment-permuted layout.
__global__ __launch_bounds__(256, 2)
void k_attn(const u16* __restrict__ Qb, const u16* __restrict__ Kb,
            const u16* __restrict__ Vt, const u16* __restrict__ BiasE,
            u16* __restrict__ Ob) {
  __shared__ u16 Ks[2][64 * 64];
  __shared__ u16 Vs[2][64 * 64];

  const int tid = threadIdx.x, lane = tid & 63, w = tid >> 6;
  const int g = lane >> 4, q = lane & 15;
  const int qt = blockIdx.x, h = blockIdx.y, b = blockIdx.z;
  const int q0 = qt * 64;
  const size_t bh = (size_t)(b * 16 + h);

  // Q as B-operand (prescaled by 0.125*log2e at projection)
  const u16* Qrow = Qb + (bh * 2048 + q0 + w * 16 + q) * 64;
  bf16x8 bq0 = *(const bf16x8*)(Qrow + g * 8);
  bf16x8 bq1 = *(const bf16x8*)(Qrow + 32 + g * 8);

  f32x4 acc[4] = {};
  float mrun = -1e30f, lrun = 0.f;

  const int sA = tid, sB = tid + 256;
  const int r0 = sA >> 3, c0 = (sA & 7) ^ (r0 & 7);
  const int r1 = sB >> 3, c1 = (sB & 7) ^ (r1 & 7);
  const u16* Kg = Kb + bh * 2048 * 64;
  const u16* Vg = Vt + bh * 64 * 2048;
  const int ld0 = (tid & ~63) * 8, ld1 = ld0 + 2048;

  const u16* brow = BiasE + ((size_t)b * 2048 + q0 + w * 16 + q) * 2048 + g * 16;

  // prologue: tile 0 + bias 0
  GLD16(Kg + (size_t)r0 * 64 + c0 * 8, &Ks[0][ld0]);
  GLD16(Kg + (size_t)r1 * 64 + c1 * 8, &Ks[0][ld1]);
  GLD16(Vg + (size_t)r0 * 2048 + c0 * 8, &Vs[0][ld0]);
  GLD16(Vg + (size_t)r1 * 2048 + c1 * 8, &Vs[0][ld1]);
  u16x8 bbA0 = *(const u16x8*)(brow);
  u16x8 bbA1 = *(const u16x8*)(brow + 8);
  u16x8 bbB0 = {}, bbB1 = {};
  WAITVM_BAR(2);

#define ATTN_STEP(BUF, B0, B1, NB0, NB1, T)                                   \
  {                                                                           \
    const int nkv = (((T) + 1) & 31) * 64;                                    \
    GLD16(Kg + (size_t)(nkv + r0) * 64 + c0 * 8, &Ks[(BUF) ^ 1][ld0]);        \
    GLD16(Kg + (size_t)(nkv + r1) * 64 + c1 * 8, &Ks[(BUF) ^ 1][ld1]);        \
    GLD16(Vg + (size_t)r0 * 2048 + nkv + c0 * 8, &Vs[(BUF) ^ 1][ld0]);        \
    GLD16(Vg + (size_t)r1 * 2048 + nkv + c1 * 8, &Vs[(BUF) ^ 1][ld1]);        \
    NB0 = *(const u16x8*)(brow + nkv);                                        \
    NB1 = *(const u16x8*)(brow + nkv + 8);                                    \
    WAITVM_BAR(6);                                                            \
    f32x4 sc[4];                                                              \
    __builtin_amdgcn_s_setprio(1);                                            \
    _Pragma("unroll")                                                         \
    for (int c = 0; c < 4; c++) {                                             \
      const int kvr = c * 16 + q;                                             \
      f32x4 z = {};                                                           \
      bf16x8 ak0 = *(const bf16x8*)((const char*)&Ks[BUF][0] + kvr * 128 +    \
                                    ((g * 16) ^ ((kvr & 7) << 4)));           \
      bf16x8 ak1 = *(const bf16x8*)((const char*)&Ks[BUF][0] + kvr * 128 +    \
                                    ((64 + g * 16) ^ ((kvr & 7) << 4)));      \
      z = MFMA16(ak0, bq0, z);                                                \
      z = MFMA16(ak1, bq1, z);                                                \
      sc[c] = z;                                                              \
    }                                                                         \
    __builtin_amdgcn_s_setprio(0);                                            \
    float p[4][4];                                                            \
    float tmax = -3e38f;                                                      \
    _Pragma("unroll")                                                         \
    for (int c = 0; c < 4; c++) {                                             \
      _Pragma("unroll")                                                       \
      for (int r = 0; r < 4; r++) {                                           \
        unsigned braw =                                                       \
            (unsigned)(c < 2 ? (B0)[c * 4 + r] : (B1)[(c - 2) * 4 + r]);      \
        float s = sc[c][r] + __uint_as_float(braw << 16);                     \
        p[c][r] = s;                                                          \
        tmax = fmaxf(tmax, s);                                                \
      }                                                                       \
    }                                                                         \
    tmax = fmaxf(tmax, __shfl_xor(tmax, 16, 64));                             \
    tmax = fmaxf(tmax, __shfl_xor(tmax, 32, 64));                             \
    float mnew = fmaxf(mrun, tmax);                                           \
    float alpha = EXP2(mrun - mnew);                                          \
    mrun = mnew;                                                              \
    float rsum = 0.f;                                                         \
    _Pragma("unroll")                                                         \
    for (int c = 0; c < 4; c++)                                               \
      _Pragma("unroll")                                                       \
      for (int r = 0; r < 4; r++) {                                           \
        p[c][r] = EXP2(p[c][r] - mnew);                                       \
        rsum += p[c][r];                                                      \
      }                                                                       \
    rsum += __shfl_xor(rsum, 16, 64);                                         \
    rsum += __shfl_xor(rsum, 32, 64);                                         \
    lrun = lrun * alpha + rsum;                                               \
    _Pragma("unroll")                                                         \
    for (int j = 0; j < 4; j++) {                                             \
      float aj = __shfl(alpha, g * 4 + j, 64);                                \
      _Pragma("unroll")                                                       \
      for (int d = 0; d < 4; d++) acc[d][j] *= aj;                            \
    }                                                                         \
    __builtin_amdgcn_s_setprio(1);                                            \
    _Pragma("unroll")                                                         \
    for (int c = 0; c < 4; c++) {                                             \
      union { unsigned u[2]; bf16x4 v; } pa;                                  \
      pa.u[0] = pk2(p[c][0], p[c][1]);                                        \
      pa.u[1] = pk2(p[c][2], p[c][3]);                                        \
      _Pragma("unroll")                                                       \
      for (int d = 0; d < 4; d++) {                                           \
        const int dr = d * 16 + q;                                            \
        bf16x4 vb = *(const bf16x4*)((const char*)&Vs[BUF][0] + dr * 128 +    \
                                     ((c * 32 + g * 8) ^ ((dr & 7) << 4)));   \
        acc[d] = MFMA_PV(pa.v, vb, acc[d]);                                   \
      }                                                                       \
    }                                                                         \
    __builtin_amdgcn_s_setprio(0);                                            \
    BAR();                                                                    \
  }

  for (int t = 0; t < 32; t += 2) {
    ATTN_STEP(0, bbA0, bbA1, bbB0, bbB1, t)
    ATTN_STEP(1, bbB0, bbB1, bbA0, bbA1, t + 1)
  }
#undef ATTN_STEP

  // epilogue: O[q'=4g+j][d], divide by l[q'], write bf16 [B,NQ,1024]
  float linv = 1.0f / lrun;
#pragma unroll
  for (int j = 0; j < 4; j++) {
    float li = __shfl(linv, g * 4 + j, 64);
    int qq = q0 + w * 16 + g * 4 + j;
#pragma unroll
    for (int d = 0; d < 4; d++)
      Ob[((size_t)b * 2048 + qq) * 1024 + h * 64 + d * 16 + q] =
          f2bf(acc[d][j] * li);
  }
}

// ---------------------------------------------------------------------------
extern "C" void kernel_launch(void* const* d_in, const int* in_sizes, int n_in,
                              void* d_out, int out_size, void* d_ws,
                              size_t ws_size, hipStream_t stream) {
  (void)in_sizes; (void)n_in; (void)out_size; (void)ws_size;
  const float* q_in = (const float*)d_in[0];
  const float* k_in = (const float*)d_in[1];
  const float* v_in = (const float*)d_in[2];
  const int* mask = (const int*)d_in[3];
  const float* attn_bias = (const float*)d_in[4];
  const float* w_q = (const float*)d_in[5];
  const float* b_q = (const float*)d_in[6];
  const float* w_k = (const float*)d_in[7];
  const float* b_k = (const float*)d_in[8];
  const float* w_v = (const float*)d_in[9];
  const float* b_v = (const float*)d_in[10];
  const float* w_o = (const float*)d_in[11];
  const float* b_o = (const float*)d_in[12];

  const size_t MB = 1u << 20;
  char* ws = (char*)d_ws;
  u16* XQ = (u16*)(ws + 0 * MB);
  u16* XK = (u16*)(ws + 8 * MB);
  u16* XV = (u16*)(ws + 16 * MB);
  u16* WQ = (u16*)(ws + 24 * MB);
  u16* WK = (u16*)(ws + 26 * MB);
  u16* WV = (u16*)(ws + 28 * MB);
  u16* WO = (u16*)(ws + 30 * MB);
  u16* Qb = (u16*)(ws + 32 * MB);
  u16* Kb = (u16*)(ws + 40 * MB);
  u16* Vt = (u16*)(ws + 48 * MB);
  u16* Ob = (u16*)(ws + 56 * MB);
  u16* BiasE = (u16*)(ws + 0 * MB);  // reuses XQ/XK/XV region (dead by then)

  ConvArgs ca;
  ca.d[0] = {q_in, XQ, 4096 * 1024};
  ca.d[1] = {k_in, XK, 4096 * 1024};
  ca.d[2] = {v_in, XV, 4096 * 1024};
  ca.d[3] = {w_q, WQ, 1024 * 1024};
  ca.d[4] = {w_k, WK, 1024 * 1024};
  ca.d[5] = {w_v, WV, 1024 * 1024};
  ca.d[6] = {w_o, WO, 1024 * 1024};
  k_convert<<<dim3(2048, 7), 256, 0, stream>>>(ca);

  dim3 ggrid(8, 32);  // N/128, M/128
  const float QSCALE = 0.125f * 1.44269504f;
  k_gemm_bt<<<ggrid, 256, 0, stream>>>(XQ, WQ, b_q, (void*)Qb, 0, QSCALE);
  k_gemm_bt<<<ggrid, 256, 0, stream>>>(XK, WK, b_k, (void*)Kb, 0, 1.0f);
  k_gemm_bt<<<ggrid, 256, 0, stream>>>(XV, WV, b_v, (void*)Vt, 1, 1.0f);

  k_biasprep<<<2048, 256, 0, stream>>>(attn_bias, mask, BiasE);

  k_attn<<<dim3(32, 16, 2), 256, 0, stream>>>(Qb, Kb, Vt, BiasE, Ob);

  k_gemm_bt<<<ggrid, 256, 0, stream>>>(Ob, WO, b_o, d_out, 2, 1.0f);
}

// Round 4
// 169.304 us; speedup vs baseline: 1.5517x; 1.2171x over previous
//
#include <hip/hip_runtime.h>

// ---------------------------------------------------------------------------
// MultiHeadAttention forward, MI355X/gfx950.
// prep(convert+biasmask) -> merged GEMM QKV -> flash attention -> GEMM O
// Round 4: QBLK=128 attn (2 sub-tiles/wave, shared K/V frags), defer-max,
// XCD-clustered attn grid, merged QKV GEMM (3 blocks/CU), BM=64 O-proj.
// ---------------------------------------------------------------------------

typedef short bf16x8 __attribute__((ext_vector_type(8)));
typedef short bf16x4 __attribute__((ext_vector_type(4)));
typedef float f32x4 __attribute__((ext_vector_type(4)));
typedef int i32x4 __attribute__((ext_vector_type(4)));
typedef unsigned short u16;
typedef unsigned short u16x8 __attribute__((ext_vector_type(8)));
typedef unsigned short u16x4 __attribute__((ext_vector_type(4)));

#define MFMA16(a, b, c) __builtin_amdgcn_mfma_f32_16x16x32_bf16((a), (b), (c), 0, 0, 0)
#define GLD16(gp, lp)                                                     \
  __builtin_amdgcn_global_load_lds(                                       \
      (const __attribute__((address_space(1))) void*)(gp),                \
      (__attribute__((address_space(3))) void*)(lp), 16, 0, 0)

#define WAITVM_BAR(N) asm volatile("s_waitcnt vmcnt(" #N ")\ns_barrier" ::: "memory")
#define BAR() asm volatile("s_barrier" ::: "memory")

#if __has_builtin(__builtin_amdgcn_exp2f)
#define EXP2(x) __builtin_amdgcn_exp2f(x)
#else
#define EXP2(x) exp2f(x)
#endif

__device__ __forceinline__ f32x4 MFMA_PV(bf16x4 a, bf16x4 b, f32x4 c) {
#if __has_builtin(__builtin_amdgcn_mfma_f32_16x16x16bf16_1k)
  return __builtin_amdgcn_mfma_f32_16x16x16bf16_1k(a, b, c, 0, 0, 0);
#else
  asm("v_mfma_f32_16x16x16_bf16 %0, %1, %2, %0" : "+v"(c) : "v"(a), "v"(b));
  return c;
#endif
}

__device__ __forceinline__ u16 f2bf(float f) {
  union { float f; unsigned u; } v; v.f = f;
  return (u16)((v.u + 0x7fffu + ((v.u >> 16) & 1u)) >> 16);
}
__device__ __forceinline__ unsigned pk2(float x, float y) {
  union { float f; unsigned u; } a, b;
  a.f = x; b.f = y;
  return ((a.u + 0x8000u) >> 16) | ((b.u + 0x8000u) & 0xffff0000u);
}

// ---------------- prep: f32->bf16 convert (y<7) + bias/mask prep (y==7) ----
struct ConvDesc { const float* src; u16* dst; int n; };
struct ConvArgs { ConvDesc d[7]; };

__device__ __forceinline__ void biasprep_body(const float* __restrict__ bias,
                                              const int* __restrict__ mask,
                                              u16* __restrict__ out, int i) {
  const int o0 = i * 16;
  const int rowg = o0 >> 11;
  const int b = rowg >> 11;
  const int off = o0 & 2047;
  const int a = off >> 6, g = (off >> 4) & 3;
  const float* src = bias + (size_t)rowg * 2048 + a * 64 + g * 4;
  const int* msk = mask + b * 2048 + a * 64 + g * 4;
  u16x8 w0 = {}, w1 = {};
#pragma unroll
  for (int c = 0; c < 4; c++) {
    f32x4 v = *(const f32x4*)(src + c * 16);
    i32x4 m = *(const i32x4*)(msk + c * 16);
#pragma unroll
    for (int j = 0; j < 4; j++) {
      u16 val = (m[j] != 0) ? f2bf(v[j] * 1.44269504f) : (u16)0xFF80;
      if (c < 2) w0[c * 4 + j] = val;
      else       w1[(c - 2) * 4 + j] = val;
    }
  }
  *(u16x8*)(out + o0) = w0;
  *(u16x8*)(out + o0 + 8) = w1;
}

__global__ __launch_bounds__(256)
void k_prep(ConvArgs a, const float* __restrict__ bias,
            const int* __restrict__ mask, u16* __restrict__ bout) {
  if (blockIdx.y == 7) {
    biasprep_body(bias, mask, bout, blockIdx.x * 256 + threadIdx.x);
    return;
  }
  ConvDesc cd = a.d[blockIdx.y];
  int i = (blockIdx.x * 256 + threadIdx.x) * 8;
  if (i >= cd.n) return;
  const float4* s = (const float4*)(cd.src + i);
  float4 f0 = s[0], f1 = s[1];
  u16x8 o;
  o[0] = f2bf(f0.x); o[1] = f2bf(f0.y); o[2] = f2bf(f0.z); o[3] = f2bf(f0.w);
  o[4] = f2bf(f1.x); o[5] = f2bf(f1.y); o[6] = f2bf(f1.z); o[7] = f2bf(f1.w);
  *(u16x8*)(cd.dst + i) = o;
}

__global__ __launch_bounds__(256)
void k_biasprep(const float* __restrict__ bias, const int* __restrict__ mask,
                u16* __restrict__ out) {
  biasprep_body(bias, mask, out, blockIdx.x * 256 + threadIdx.x);
}

// ---------------- bf16 GEMM body: C = (A[M,K] * B[N,K]^T + bias)*oscale ----
// BM = MF*32, BN = 128, BK = 32, 4 waves (2x2). Counted-vmcnt double buffer.
template <int MF>
__device__ __forceinline__ void gemm_impl(const u16* __restrict__ A,
                                          const u16* __restrict__ Bw,
                                          const float* __restrict__ bias,
                                          void* __restrict__ outp, int mode,
                                          float oscale) {
  __shared__ u16 As[2][MF * 1024];
  __shared__ u16 Bs[2][4096];
  const int tid = threadIdx.x;
  const int lane = tid & 63;
  const int wv = tid >> 6;
  const int wr = wv >> 1, wc = wv & 1;
  const int m0 = blockIdx.y * (MF * 32), n0 = blockIdx.x * 128;

  f32x4 acc[MF][4] = {};

  const int s0 = tid, s1 = 256 + tid;
  const int r0 = s0 >> 2, c0 = (s0 & 3) ^ (r0 & 3);
  const int r1 = s1 >> 2, c1 = (s1 & 3) ^ (r1 & 3);
  const u16* gA0 = A + (size_t)(m0 + r0) * 1024 + c0 * 8;
  const u16* gA1 = A + (size_t)(m0 + r1) * 1024 + c1 * 8;  // MF==4 only
  const u16* gB0 = Bw + (size_t)(n0 + r0) * 1024 + c0 * 8;
  const u16* gB1 = Bw + (size_t)(n0 + r1) * 1024 + c1 * 8;
  u16* lA0 = &As[0][(tid & ~63) * 8];
  u16* lB0 = &Bs[0][(tid & ~63) * 8];

  // prologue: stage k=0 into buf0
  GLD16(gA0, lA0);
  if constexpr (MF == 4) GLD16(gA1, lA0 + 2048);
  GLD16(gB0, lB0);
  GLD16(gB1, lB0 + 2048);
  WAITVM_BAR(0);

#define GSTEP(BUF, K0)                                                     \
  {                                                                        \
    const int nk = ((K0) + 32) & 1023;                                     \
    GLD16(gA0 + nk, lA0 + ((BUF) ^ 1) * (MF * 1024));                      \
    if constexpr (MF == 4)                                                 \
      GLD16(gA1 + nk, lA0 + 2048 + ((BUF) ^ 1) * (MF * 1024));             \
    GLD16(gB0 + nk, lB0 + ((BUF) ^ 1) * 4096);                             \
    GLD16(gB1 + nk, lB0 + 2048 + ((BUF) ^ 1) * 4096);                      \
    if constexpr (MF == 4) { WAITVM_BAR(4); } else { WAITVM_BAR(3); }      \
    bf16x8 af[MF], bfr[4];                                                 \
    _Pragma("unroll")                                                      \
    for (int mi = 0; mi < MF; mi++) {                                      \
      int row = wr * (MF * 16) + mi * 16 + (lane & 15);                    \
      int byt = row * 64 + (((lane >> 4) * 16) ^ ((row & 3) << 4));        \
      af[mi] = *(const bf16x8*)((const char*)&As[BUF][0] + byt);           \
    }                                                                      \
    _Pragma("unroll")                                                      \
    for (int ni = 0; ni < 4; ni++) {                                       \
      int row = wc * 64 + ni * 16 + (lane & 15);                           \
      int byt = row * 64 + (((lane >> 4) * 16) ^ ((row & 3) << 4));        \
      bfr[ni] = *(const bf16x8*)((const char*)&Bs[BUF][0] + byt);          \
    }                                                                      \
    __builtin_amdgcn_s_setprio(1);                                         \
    _Pragma("unroll")                                                      \
    for (int mi = 0; mi < MF; mi++)                                        \
      _Pragma("unroll")                                                    \
      for (int ni = 0; ni < 4; ni++)                                       \
        acc[mi][ni] = MFMA16(af[mi], bfr[ni], acc[mi][ni]);                \
    __builtin_amdgcn_s_setprio(0);                                         \
    BAR();                                                                 \
  }

  for (int k0 = 0; k0 < 1024; k0 += 64) {
    GSTEP(0, k0)
    GSTEP(1, k0 + 32)
  }
#undef GSTEP

#pragma unroll
  for (int ni = 0; ni < 4; ni++) {
    int n = n0 + wc * 64 + ni * 16 + (lane & 15);
    float bv = bias[n];
#pragma unroll
    for (int mi = 0; mi < MF; mi++) {
      int mb = m0 + wr * (MF * 16) + mi * 16 + (lane >> 4) * 4;
      if (mode == 2) {
        float* O = (float*)outp;
#pragma unroll
        for (int r = 0; r < 4; r++)
          O[(size_t)(mb + r) * 1024 + n] = (acc[mi][ni][r] + bv) * oscale;
      } else if (mode == 0) {
        u16* O = (u16*)outp;
        int b = mb >> 11, q = mb & 2047;
        int h = n >> 6, dk = n & 63;
        size_t base = ((size_t)(b * 16 + h) * 2048 + q) * 64 + dk;
#pragma unroll
        for (int r = 0; r < 4; r++)
          O[base + (size_t)r * 64] = f2bf((acc[mi][ni][r] + bv) * oscale);
      } else {  // mode 1: V^T [B,H,64,NK]
        u16* O = (u16*)outp;
        int b = mb >> 11, kv = mb & 2047;
        int h = n >> 6, dk = n & 63;
        u16x4 pk;
#pragma unroll
        for (int r = 0; r < 4; r++) pk[r] = f2bf((acc[mi][ni][r] + bv) * oscale);
        *(u16x4*)((u16*)O + ((size_t)((b * 16 + h) * 64 + dk)) * 2048 + kv) = pk;
      }
    }
  }
}

struct GemmDesc { const u16* A; const u16* W; const float* bias; void* out;
                  int mode; float oscale; };
struct Gemm3 { GemmDesc d[3]; };

__global__ __launch_bounds__(256, 2) void k_gemm_qkv(Gemm3 g3) {
  GemmDesc gd = g3.d[blockIdx.z];
  gemm_impl<4>(gd.A, gd.W, gd.bias, gd.out, gd.mode, gd.oscale);
}
__global__ __launch_bounds__(256, 2)
void k_gemm_o(const u16* __restrict__ A, const u16* __restrict__ W,
              const float* __restrict__ bias, float* __restrict__ out) {
  gemm_impl<2>(A, W, bias, out, 2, 1.0f);
}

// ---------------- flash attention, QBLK=128 -------------------------------
// grid (h=16, b=2, qt=16): same (h,b) -> same XCD (id mod 8). 256 threads,
// 4 waves; wave owns 32 q rows as 2 sub-tiles of 16. K/V LDS fragments are
// shared across subs. Counted-vmcnt double buffer; defer-max rescale skip.
__global__ __launch_bounds__(256, 2)
void k_attn(const u16* __restrict__ Qb, const u16* __restrict__ Kb,
            const u16* __restrict__ Vt, const u16* __restrict__ BiasE,
            u16* __restrict__ Ob) {
  __shared__ u16 Ks[2][64 * 64];
  __shared__ u16 Vs[2][64 * 64];

  const int tid = threadIdx.x, lane = tid & 63, w = tid >> 6;
  const int g = lane >> 4, q = lane & 15;
  const int h = blockIdx.x, b = blockIdx.y, qt = blockIdx.z;
  const int q0 = qt * 128;
  const size_t bh = (size_t)(b * 16 + h);

  // Q as B-operand (prescaled by 0.125*log2e at projection), per sub-tile
  bf16x8 bq0[2], bq1[2];
#pragma unroll
  for (int s = 0; s < 2; s++) {
    const u16* Qrow = Qb + (bh * 2048 + q0 + w * 32 + s * 16 + q) * 64;
    bq0[s] = *(const bf16x8*)(Qrow + g * 8);
    bq1[s] = *(const bf16x8*)(Qrow + 32 + g * 8);
  }

  f32x4 acc[2][4] = {};
  float mrun[2] = {-1e30f, -1e30f}, lrun[2] = {0.f, 0.f};

  const int sA = tid, sB = tid + 256;
  const int r0 = sA >> 3, c0 = (sA & 7) ^ (r0 & 7);
  const int r1 = sB >> 3, c1 = (sB & 7) ^ (r1 & 7);
  const u16* Kg = Kb + bh * 2048 * 64;
  const u16* Vg = Vt + bh * 64 * 2048;
  const int ld0 = (tid & ~63) * 8, ld1 = ld0 + 2048;

  const u16* brow[2];
#pragma unroll
  for (int s = 0; s < 2; s++)
    brow[s] = BiasE + ((size_t)b * 2048 + q0 + w * 32 + s * 16 + q) * 2048 + g * 16;

  // prologue: stage tile 0, full drain, then prefetch bias tile 0
  GLD16(Kg + (size_t)r0 * 64 + c0 * 8, &Ks[0][ld0]);
  GLD16(Kg + (size_t)r1 * 64 + c1 * 8, &Ks[0][ld1]);
  GLD16(Vg + (size_t)r0 * 2048 + c0 * 8, &Vs[0][ld0]);
  GLD16(Vg + (size_t)r1 * 2048 + c1 * 8, &Vs[0][ld1]);
  WAITVM_BAR(0);
  u16x8 bbA[2][2], bbB[2][2];
#pragma unroll
  for (int s = 0; s < 2; s++) {
    bbA[s][0] = *(const u16x8*)(brow[s]);
    bbA[s][1] = *(const u16x8*)(brow[s] + 8);
  }

#define ATTN_STEP(BUF, BBU, BBF, T)                                           \
  {                                                                           \
    const int nkv = (((T) + 1) & 31) * 64;                                    \
    GLD16(Kg + (size_t)(nkv + r0) * 64 + c0 * 8, &Ks[(BUF) ^ 1][ld0]);        \
    GLD16(Kg + (size_t)(nkv + r1) * 64 + c1 * 8, &Ks[(BUF) ^ 1][ld1]);        \
    GLD16(Vg + (size_t)r0 * 2048 + nkv + c0 * 8, &Vs[(BUF) ^ 1][ld0]);        \
    GLD16(Vg + (size_t)r1 * 2048 + nkv + c1 * 8, &Vs[(BUF) ^ 1][ld1]);        \
    _Pragma("unroll")                                                         \
    for (int s = 0; s < 2; s++) {                                             \
      BBF[s][0] = *(const u16x8*)(brow[s] + nkv);                             \
      BBF[s][1] = *(const u16x8*)(brow[s] + nkv + 8);                         \
    }                                                                         \
    WAITVM_BAR(8);                                                            \
    f32x4 sc[2][4];                                                           \
    __builtin_amdgcn_s_setprio(1);                                            \
    _Pragma("unroll")                                                         \
    for (int c = 0; c < 4; c++) {                                             \
      const int kvr = c * 16 + q;                                             \
      bf16x8 ak0 = *(const bf16x8*)((const char*)&Ks[BUF][0] + kvr * 128 +    \
                                    ((g * 16) ^ ((kvr & 7) << 4)));           \
      bf16x8 ak1 = *(const bf16x8*)((const char*)&Ks[BUF][0] + kvr * 128 +    \
                                    ((64 + g * 16) ^ ((kvr & 7) << 4)));      \
      _Pragma("unroll")                                                       \
      for (int s = 0; s < 2; s++) {                                           \
        f32x4 z = {};                                                         \
        z = MFMA16(ak0, bq0[s], z);                                           \
        z = MFMA16(ak1, bq1[s], z);                                           \
        sc[s][c] = z;                                                         \
      }                                                                       \
    }                                                                         \
    __builtin_amdgcn_s_setprio(0);                                            \
    float p[2][4][4];                                                         \
    float tmax[2] = {-3e38f, -3e38f};                                         \
    _Pragma("unroll")                                                         \
    for (int s = 0; s < 2; s++) {                                             \
      _Pragma("unroll")                                                       \
      for (int c = 0; c < 4; c++)                                             \
        _Pragma("unroll")                                                     \
        for (int r = 0; r < 4; r++) {                                         \
          unsigned braw =                                                     \
              (unsigned)(c < 2 ? (BBU)[s][0][c * 4 + r]                       \
                               : (BBU)[s][1][(c - 2) * 4 + r]);               \
          float sv = sc[s][c][r] + __uint_as_float(braw << 16);               \
          p[s][c][r] = sv;                                                    \
          tmax[s] = fmaxf(tmax[s], sv);                                       \
        }                                                                     \
      tmax[s] = fmaxf(tmax[s], __shfl_xor(tmax[s], 16, 64));                  \
      tmax[s] = fmaxf(tmax[s], __shfl_xor(tmax[s], 32, 64));                  \
    }                                                                         \
    if (__any((tmax[0] > mrun[0]) | (tmax[1] > mrun[1]))) {                   \
      _Pragma("unroll")                                                       \
      for (int s = 0; s < 2; s++) {                                           \
        float mnew = fmaxf(mrun[s], tmax[s]);                                 \
        float alpha = EXP2(mrun[s] - mnew);                                   \
        mrun[s] = mnew;                                                       \
        lrun[s] *= alpha;                                                     \
        _Pragma("unroll")                                                     \
        for (int j = 0; j < 4; j++) {                                         \
          float aj = __shfl(alpha, g * 4 + j, 64);                            \
          _Pragma("unroll")                                                   \
          for (int d = 0; d < 4; d++) acc[s][d][j] *= aj;                     \
        }                                                                     \
      }                                                                       \
    }                                                                         \
    _Pragma("unroll")                                                         \
    for (int s = 0; s < 2; s++) {                                             \
      float rsum = 0.f;                                                       \
      _Pragma("unroll")                                                       \
      for (int c = 0; c < 4; c++)                                             \
        _Pragma("unroll")                                                     \
        for (int r = 0; r < 4; r++) {                                         \
          p[s][c][r] = EXP2(p[s][c][r] - mrun[s]);                            \
          rsum += p[s][c][r];                                                 \
        }                                                                     \
      rsum += __shfl_xor(rsum, 16, 64);                                       \
      rsum += __shfl_xor(rsum, 32, 64);                                       \
      lrun[s] += rsum;                                                        \
    }                                                                         \
    __builtin_amdgcn_s_setprio(1);                                            \
    _Pragma("unroll")                                                         \
    for (int c = 0; c < 4; c++) {                                             \
      union { unsigned u[2]; bf16x4 v; } pa[2];                               \
      _Pragma("unroll")                                                       \
      for (int s = 0; s < 2; s++) {                                           \
        pa[s].u[0] = pk2(p[s][c][0], p[s][c][1]);                             \
        pa[s].u[1] = pk2(p[s][c][2], p[s][c][3]);                             \
      }                                                                       \
      _Pragma("unroll")                                                       \
      for (int d = 0; d < 4; d++) {                                           \
        const int dr = d * 16 + q;                                            \
        bf16x4 vb = *(const bf16x4*)((const char*)&Vs[BUF][0] + dr * 128 +    \
                                     ((c * 32 + g * 8) ^ ((dr & 7) << 4)));   \
        _Pragma("unroll")                                                     \
        for (int s = 0; s < 2; s++) acc[s][d] = MFMA_PV(pa[s].v, vb, acc[s][d]); \
      }                                                                       \
    }                                                                         \
    __builtin_amdgcn_s_setprio(0);                                            \
    BAR();                                                                    \
  }

  for (int t = 0; t < 32; t += 2) {
    ATTN_STEP(0, bbA, bbB, t)
    ATTN_STEP(1, bbB, bbA, t + 1)
  }
#undef ATTN_STEP

  // epilogue
#pragma unroll
  for (int s = 0; s < 2; s++) {
    float linv = 1.0f / lrun[s];
#pragma unroll
    for (int j = 0; j < 4; j++) {
      float li = __shfl(linv, g * 4 + j, 64);
      int qq = q0 + w * 32 + s * 16 + g * 4 + j;
#pragma unroll
      for (int d = 0; d < 4; d++)
        Ob[((size_t)b * 2048 + qq) * 1024 + h * 64 + d * 16 + q] =
            f2bf(acc[s][d][j] * li);
    }
  }
}

// ---------------------------------------------------------------------------
extern "C" void kernel_launch(void* const* d_in, const int* in_sizes, int n_in,
                              void* d_out, int out_size, void* d_ws,
                              size_t ws_size, hipStream_t stream) {
  (void)in_sizes; (void)n_in; (void)out_size;
  const float* q_in = (const float*)d_in[0];
  const float* k_in = (const float*)d_in[1];
  const float* v_in = (const float*)d_in[2];
  const int* mask = (const int*)d_in[3];
  const float* attn_bias = (const float*)d_in[4];
  const float* w_q = (const float*)d_in[5];
  const float* b_q = (const float*)d_in[6];
  const float* w_k = (const float*)d_in[7];
  const float* b_k = (const float*)d_in[8];
  const float* w_v = (const float*)d_in[9];
  const float* b_v = (const float*)d_in[10];
  const float* w_o = (const float*)d_in[11];
  const float* b_o = (const float*)d_in[12];

  const size_t MB = 1u << 20;
  char* ws = (char*)d_ws;
  u16* XQ = (u16*)(ws + 0 * MB);
  u16* XK = (u16*)(ws + 8 * MB);
  u16* XV = (u16*)(ws + 16 * MB);
  u16* WQ = (u16*)(ws + 24 * MB);
  u16* WK = (u16*)(ws + 26 * MB);
  u16* WV = (u16*)(ws + 28 * MB);
  u16* WO = (u16*)(ws + 30 * MB);
  u16* Qb = (u16*)(ws + 32 * MB);
  u16* Kb = (u16*)(ws + 40 * MB);
  u16* Vt = (u16*)(ws + 48 * MB);
  u16* Ob = (u16*)(ws + 56 * MB);
  const bool merged = ws_size >= (size_t)80 * MB;
  u16* BiasE = (u16*)(ws + (merged ? 64 : 0) * MB);

  ConvArgs ca;
  ca.d[0] = {q_in, XQ, 4096 * 1024};
  ca.d[1] = {k_in, XK, 4096 * 1024};
  ca.d[2] = {v_in, XV, 4096 * 1024};
  ca.d[3] = {w_q, WQ, 1024 * 1024};
  ca.d[4] = {w_k, WK, 1024 * 1024};
  ca.d[5] = {w_v, WV, 1024 * 1024};
  ca.d[6] = {w_o, WO, 1024 * 1024};
  k_prep<<<dim3(2048, merged ? 8 : 7), 256, 0, stream>>>(ca, attn_bias, mask,
                                                         BiasE);

  const float QSCALE = 0.125f * 1.44269504f;
  Gemm3 g3;
  g3.d[0] = {XQ, WQ, b_q, (void*)Qb, 0, QSCALE};
  g3.d[1] = {XK, WK, b_k, (void*)Kb, 0, 1.0f};
  g3.d[2] = {XV, WV, b_v, (void*)Vt, 1, 1.0f};
  k_gemm_qkv<<<dim3(8, 32, 3), 256, 0, stream>>>(g3);

  if (!merged) k_biasprep<<<2048, 256, 0, stream>>>(attn_bias, mask, BiasE);

  k_attn<<<dim3(16, 2, 16), 256, 0, stream>>>(Qb, Kb, Vt, BiasE, Ob);

  k_gemm_o<<<dim3(8, 64), 256, 0, stream>>>(Ob, WO, b_o, (float*)d_out);
}

// Round 5
// 160.949 us; speedup vs baseline: 1.6323x; 1.0519x over previous
//
#include <hip/hip_runtime.h>

// ---------------------------------------------------------------------------
// MultiHeadAttention forward, MI355X/gfx950.
// prep(convert+biasmask) -> merged GEMM QKV -> flash attention -> GEMM O
// Round 5: attn = 512 threads / 8 waves / QBLK=128 (wave owns 16 q rows):
// keeps round-4 K/V staging amortization, restores round-3 wave parallelism.
// ---------------------------------------------------------------------------

typedef short bf16x8 __attribute__((ext_vector_type(8)));
typedef short bf16x4 __attribute__((ext_vector_type(4)));
typedef float f32x4 __attribute__((ext_vector_type(4)));
typedef int i32x4 __attribute__((ext_vector_type(4)));
typedef unsigned short u16;
typedef unsigned short u16x8 __attribute__((ext_vector_type(8)));
typedef unsigned short u16x4 __attribute__((ext_vector_type(4)));

#define MFMA16(a, b, c) __builtin_amdgcn_mfma_f32_16x16x32_bf16((a), (b), (c), 0, 0, 0)
#define GLD16(gp, lp)                                                     \
  __builtin_amdgcn_global_load_lds(                                       \
      (const __attribute__((address_space(1))) void*)(gp),                \
      (__attribute__((address_space(3))) void*)(lp), 16, 0, 0)

#define WAITVM_BAR(N) asm volatile("s_waitcnt vmcnt(" #N ")\ns_barrier" ::: "memory")
#define BAR() asm volatile("s_barrier" ::: "memory")

#if __has_builtin(__builtin_amdgcn_exp2f)
#define EXP2(x) __builtin_amdgcn_exp2f(x)
#else
#define EXP2(x) exp2f(x)
#endif

__device__ __forceinline__ f32x4 MFMA_PV(bf16x4 a, bf16x4 b, f32x4 c) {
#if __has_builtin(__builtin_amdgcn_mfma_f32_16x16x16bf16_1k)
  return __builtin_amdgcn_mfma_f32_16x16x16bf16_1k(a, b, c, 0, 0, 0);
#else
  asm("v_mfma_f32_16x16x16_bf16 %0, %1, %2, %0" : "+v"(c) : "v"(a), "v"(b));
  return c;
#endif
}

__device__ __forceinline__ u16 f2bf(float f) {
  union { float f; unsigned u; } v; v.f = f;
  return (u16)((v.u + 0x7fffu + ((v.u >> 16) & 1u)) >> 16);
}
__device__ __forceinline__ unsigned pk2(float x, float y) {
  union { float f; unsigned u; } a, b;
  a.f = x; b.f = y;
  return ((a.u + 0x8000u) >> 16) | ((b.u + 0x8000u) & 0xffff0000u);
}

// ---------------- prep: f32->bf16 convert (y<7) + bias/mask prep (y==7) ----
struct ConvDesc { const float* src; u16* dst; int n; };
struct ConvArgs { ConvDesc d[7]; };

__device__ __forceinline__ void biasprep_body(const float* __restrict__ bias,
                                              const int* __restrict__ mask,
                                              u16* __restrict__ out, int i) {
  const int o0 = i * 16;
  const int rowg = o0 >> 11;
  const int b = rowg >> 11;
  const int off = o0 & 2047;
  const int a = off >> 6, g = (off >> 4) & 3;
  const float* src = bias + (size_t)rowg * 2048 + a * 64 + g * 4;
  const int* msk = mask + b * 2048 + a * 64 + g * 4;
  u16x8 w0 = {}, w1 = {};
#pragma unroll
  for (int c = 0; c < 4; c++) {
    f32x4 v = *(const f32x4*)(src + c * 16);
    i32x4 m = *(const i32x4*)(msk + c * 16);
#pragma unroll
    for (int j = 0; j < 4; j++) {
      u16 val = (m[j] != 0) ? f2bf(v[j] * 1.44269504f) : (u16)0xFF80;
      if (c < 2) w0[c * 4 + j] = val;
      else       w1[(c - 2) * 4 + j] = val;
    }
  }
  *(u16x8*)(out + o0) = w0;
  *(u16x8*)(out + o0 + 8) = w1;
}

__global__ __launch_bounds__(256)
void k_prep(ConvArgs a, const float* __restrict__ bias,
            const int* __restrict__ mask, u16* __restrict__ bout) {
  if (blockIdx.y == 7) {
    biasprep_body(bias, mask, bout, blockIdx.x * 256 + threadIdx.x);
    return;
  }
  ConvDesc cd = a.d[blockIdx.y];
  int i = (blockIdx.x * 256 + threadIdx.x) * 8;
  if (i >= cd.n) return;
  const float4* s = (const float4*)(cd.src + i);
  float4 f0 = s[0], f1 = s[1];
  u16x8 o;
  o[0] = f2bf(f0.x); o[1] = f2bf(f0.y); o[2] = f2bf(f0.z); o[3] = f2bf(f0.w);
  o[4] = f2bf(f1.x); o[5] = f2bf(f1.y); o[6] = f2bf(f1.z); o[7] = f2bf(f1.w);
  *(u16x8*)(cd.dst + i) = o;
}

__global__ __launch_bounds__(256)
void k_biasprep(const float* __restrict__ bias, const int* __restrict__ mask,
                u16* __restrict__ out) {
  biasprep_body(bias, mask, out, blockIdx.x * 256 + threadIdx.x);
}

// ---------------- bf16 GEMM body: C = (A[M,K] * B[N,K]^T + bias)*oscale ----
template <int MF>
__device__ __forceinline__ void gemm_impl(const u16* __restrict__ A,
                                          const u16* __restrict__ Bw,
                                          const float* __restrict__ bias,
                                          void* __restrict__ outp, int mode,
                                          float oscale) {
  __shared__ u16 As[2][MF * 1024];
  __shared__ u16 Bs[2][4096];
  const int tid = threadIdx.x;
  const int lane = tid & 63;
  const int wv = tid >> 6;
  const int wr = wv >> 1, wc = wv & 1;
  const int m0 = blockIdx.y * (MF * 32), n0 = blockIdx.x * 128;

  f32x4 acc[MF][4] = {};

  const int s0 = tid, s1 = 256 + tid;
  const int r0 = s0 >> 2, c0 = (s0 & 3) ^ (r0 & 3);
  const int r1 = s1 >> 2, c1 = (s1 & 3) ^ (r1 & 3);
  const u16* gA0 = A + (size_t)(m0 + r0) * 1024 + c0 * 8;
  const u16* gA1 = A + (size_t)(m0 + r1) * 1024 + c1 * 8;  // MF==4 only
  const u16* gB0 = Bw + (size_t)(n0 + r0) * 1024 + c0 * 8;
  const u16* gB1 = Bw + (size_t)(n0 + r1) * 1024 + c1 * 8;
  u16* lA0 = &As[0][(tid & ~63) * 8];
  u16* lB0 = &Bs[0][(tid & ~63) * 8];

  GLD16(gA0, lA0);
  if constexpr (MF == 4) GLD16(gA1, lA0 + 2048);
  GLD16(gB0, lB0);
  GLD16(gB1, lB0 + 2048);
  WAITVM_BAR(0);

#define GSTEP(BUF, K0)                                                     \
  {                                                                        \
    const int nk = ((K0) + 32) & 1023;                                     \
    GLD16(gA0 + nk, lA0 + ((BUF) ^ 1) * (MF * 1024));                      \
    if constexpr (MF == 4)                                                 \
      GLD16(gA1 + nk, lA0 + 2048 + ((BUF) ^ 1) * (MF * 1024));             \
    GLD16(gB0 + nk, lB0 + ((BUF) ^ 1) * 4096);                             \
    GLD16(gB1 + nk, lB0 + 2048 + ((BUF) ^ 1) * 4096);                      \
    if constexpr (MF == 4) { WAITVM_BAR(4); } else { WAITVM_BAR(3); }      \
    bf16x8 af[MF], bfr[4];                                                 \
    _Pragma("unroll")                                                      \
    for (int mi = 0; mi < MF; mi++) {                                      \
      int row = wr * (MF * 16) + mi * 16 + (lane & 15);                    \
      int byt = row * 64 + (((lane >> 4) * 16) ^ ((row & 3) << 4));        \
      af[mi] = *(const bf16x8*)((const char*)&As[BUF][0] + byt);           \
    }                                                                      \
    _Pragma("unroll")                                                      \
    for (int ni = 0; ni < 4; ni++) {                                       \
      int row = wc * 64 + ni * 16 + (lane & 15);                           \
      int byt = row * 64 + (((lane >> 4) * 16) ^ ((row & 3) << 4));        \
      bfr[ni] = *(const bf16x8*)((const char*)&Bs[BUF][0] + byt);          \
    }                                                                      \
    __builtin_amdgcn_s_setprio(1);                                         \
    _Pragma("unroll")                                                      \
    for (int mi = 0; mi < MF; mi++)                                        \
      _Pragma("unroll")                                                    \
      for (int ni = 0; ni < 4; ni++)                                       \
        acc[mi][ni] = MFMA16(af[mi], bfr[ni], acc[mi][ni]);                \
    __builtin_amdgcn_s_setprio(0);                                         \
    BAR();                                                                 \
  }

  for (int k0 = 0; k0 < 1024; k0 += 64) {
    GSTEP(0, k0)
    GSTEP(1, k0 + 32)
  }
#undef GSTEP

#pragma unroll
  for (int ni = 0; ni < 4; ni++) {
    int n = n0 + wc * 64 + ni * 16 + (lane & 15);
    float bv = bias[n];
#pragma unroll
    for (int mi = 0; mi < MF; mi++) {
      int mb = m0 + wr * (MF * 16) + mi * 16 + (lane >> 4) * 4;
      if (mode == 2) {
        float* O = (float*)outp;
#pragma unroll
        for (int r = 0; r < 4; r++)
          O[(size_t)(mb + r) * 1024 + n] = (acc[mi][ni][r] + bv) * oscale;
      } else if (mode == 0) {
        u16* O = (u16*)outp;
        int b = mb >> 11, q = mb & 2047;
        int h = n >> 6, dk = n & 63;
        size_t base = ((size_t)(b * 16 + h) * 2048 + q) * 64 + dk;
#pragma unroll
        for (int r = 0; r < 4; r++)
          O[base + (size_t)r * 64] = f2bf((acc[mi][ni][r] + bv) * oscale);
      } else {  // mode 1: V^T [B,H,64,NK]
        u16* O = (u16*)outp;
        int b = mb >> 11, kv = mb & 2047;
        int h = n >> 6, dk = n & 63;
        u16x4 pk;
#pragma unroll
        for (int r = 0; r < 4; r++) pk[r] = f2bf((acc[mi][ni][r] + bv) * oscale);
        *(u16x4*)((u16*)O + ((size_t)((b * 16 + h) * 64 + dk)) * 2048 + kv) = pk;
      }
    }
  }
}

struct GemmDesc { const u16* A; const u16* W; const float* bias; void* out;
                  int mode; float oscale; };
struct Gemm3 { GemmDesc d[3]; };

__global__ __launch_bounds__(256, 2) void k_gemm_qkv(Gemm3 g3) {
  GemmDesc gd = g3.d[blockIdx.z];
  gemm_impl<4>(gd.A, gd.W, gd.bias, gd.out, gd.mode, gd.oscale);
}
__global__ __launch_bounds__(256, 2)
void k_gemm_o(const u16* __restrict__ A, const u16* __restrict__ W,
              const float* __restrict__ bias, float* __restrict__ out) {
  gemm_impl<2>(A, W, bias, out, 2, 1.0f);
}

// ---------------- flash attention, QBLK=128, 512 threads / 8 waves --------
// grid (h=16, b=2, qt=16). Wave w owns q rows q0+w*16..+15. One K/V stage
// serves all 8 waves; 512 threads stage a full 64x64 bf16 tile with ONE
// GLD16 each. Counted-vmcnt double buffer; swapped QK^T; in-register P.
__global__ __launch_bounds__(512, 4)
void k_attn(const u16* __restrict__ Qb, const u16* __restrict__ Kb,
            const u16* __restrict__ Vt, const u16* __restrict__ BiasE,
            u16* __restrict__ Ob) {
  __shared__ u16 Ks[2][64 * 64];
  __shared__ u16 Vs[2][64 * 64];

  const int tid = threadIdx.x, lane = tid & 63, w = tid >> 6;
  const int g = lane >> 4, q = lane & 15;
  const int h = blockIdx.x, b = blockIdx.y, qt = blockIdx.z;
  const int q0 = qt * 128;
  const size_t bh = (size_t)(b * 16 + h);

  // Q as B-operand (prescaled by 0.125*log2e at projection)
  const u16* Qrow = Qb + (bh * 2048 + q0 + w * 16 + q) * 64;
  bf16x8 bq0 = *(const bf16x8*)(Qrow + g * 8);
  bf16x8 bq1 = *(const bf16x8*)(Qrow + 32 + g * 8);

  f32x4 acc[4] = {};
  float mrun = -1e30f, lrun = 0.f;

  // staging: 512 slots of 16B cover one 64x64 bf16 tile exactly
  const int r0 = tid >> 3, c0 = (tid & 7) ^ (r0 & 7);
  const u16* Kg = Kb + bh * 2048 * 64;
  const u16* Vg = Vt + bh * 64 * 2048;
  const int ld0 = (tid & ~63) * 8;

  const u16* brow = BiasE + ((size_t)b * 2048 + q0 + w * 16 + q) * 2048 + g * 16;

  // prologue: stage tile 0, drain, then prefetch bias tile 0
  GLD16(Kg + (size_t)r0 * 64 + c0 * 8, &Ks[0][ld0]);
  GLD16(Vg + (size_t)r0 * 2048 + c0 * 8, &Vs[0][ld0]);
  WAITVM_BAR(0);
  u16x8 bbA0 = *(const u16x8*)(brow);
  u16x8 bbA1 = *(const u16x8*)(brow + 8);
  u16x8 bbB0 = {}, bbB1 = {};

#define ATTN_STEP(BUF, B0, B1, NB0, NB1, T)                                   \
  {                                                                           \
    const int nkv = (((T) + 1) & 31) * 64;                                    \
    GLD16(Kg + (size_t)(nkv + r0) * 64 + c0 * 8, &Ks[(BUF) ^ 1][ld0]);        \
    GLD16(Vg + (size_t)r0 * 2048 + nkv + c0 * 8, &Vs[(BUF) ^ 1][ld0]);        \
    NB0 = *(const u16x8*)(brow + nkv);                                        \
    NB1 = *(const u16x8*)(brow + nkv + 8);                                    \
    WAITVM_BAR(4);                                                            \
    f32x4 sc[4];                                                              \
    __builtin_amdgcn_s_setprio(1);                                            \
    _Pragma("unroll")                                                         \
    for (int c = 0; c < 4; c++) {                                             \
      const int kvr = c * 16 + q;                                             \
      f32x4 z = {};                                                           \
      bf16x8 ak0 = *(const bf16x8*)((const char*)&Ks[BUF][0] + kvr * 128 +    \
                                    ((g * 16) ^ ((kvr & 7) << 4)));           \
      bf16x8 ak1 = *(const bf16x8*)((const char*)&Ks[BUF][0] + kvr * 128 +    \
                                    ((64 + g * 16) ^ ((kvr & 7) << 4)));      \
      z = MFMA16(ak0, bq0, z);                                                \
      z = MFMA16(ak1, bq1, z);                                                \
      sc[c] = z;                                                              \
    }                                                                         \
    __builtin_amdgcn_s_setprio(0);                                            \
    float p[4][4];                                                            \
    float tmax = -3e38f;                                                      \
    _Pragma("unroll")                                                         \
    for (int c = 0; c < 4; c++) {                                             \
      _Pragma("unroll")                                                       \
      for (int r = 0; r < 4; r++) {                                           \
        unsigned braw =                                                       \
            (unsigned)(c < 2 ? (B0)[c * 4 + r] : (B1)[(c - 2) * 4 + r]);      \
        float s = sc[c][r] + __uint_as_float(braw << 16);                     \
        p[c][r] = s;                                                          \
        tmax = fmaxf(tmax, s);                                                \
      }                                                                       \
    }                                                                         \
    tmax = fmaxf(tmax, __shfl_xor(tmax, 16, 64));                             \
    tmax = fmaxf(tmax, __shfl_xor(tmax, 32, 64));                             \
    if (__any(tmax > mrun)) {                                                 \
      float mnew = fmaxf(mrun, tmax);                                         \
      float alpha = EXP2(mrun - mnew);                                        \
      mrun = mnew;                                                            \
      lrun *= alpha;                                                          \
      _Pragma("unroll")                                                       \
      for (int j = 0; j < 4; j++) {                                           \
        float aj = __shfl(alpha, g * 4 + j, 64);                              \
        _Pragma("unroll")                                                     \
        for (int d = 0; d < 4; d++) acc[d][j] *= aj;                          \
      }                                                                       \
    }                                                                         \
    float rsum = 0.f;                                                         \
    _Pragma("unroll")                                                         \
    for (int c = 0; c < 4; c++)                                               \
      _Pragma("unroll")                                                       \
      for (int r = 0; r < 4; r++) {                                           \
        p[c][r] = EXP2(p[c][r] - mrun);                                       \
        rsum += p[c][r];                                                      \
      }                                                                       \
    rsum += __shfl_xor(rsum, 16, 64);                                         \
    rsum += __shfl_xor(rsum, 32, 64);                                         \
    lrun += rsum;                                                             \
    __builtin_amdgcn_s_setprio(1);                                            \
    _Pragma("unroll")                                                         \
    for (int c = 0; c < 4; c++) {                                             \
      union { unsigned u[2]; bf16x4 v; } pa;                                  \
      pa.u[0] = pk2(p[c][0], p[c][1]);                                        \
      pa.u[1] = pk2(p[c][2], p[c][3]);                                        \
      _Pragma("unroll")                                                       \
      for (int d = 0; d < 4; d++) {                                           \
        const int dr = d * 16 + q;                                            \
        bf16x4 vb = *(const bf16x4*)((const char*)&Vs[BUF][0] + dr * 128 +    \
                                     ((c * 32 + g * 8) ^ ((dr & 7) << 4)));   \
        acc[d] = MFMA_PV(pa.v, vb, acc[d]);                                   \
      }                                                                       \
    }                                                                         \
    __builtin_amdgcn_s_setprio(0);                                            \
    BAR();                                                                    \
  }

  for (int t = 0; t < 32; t += 2) {
    ATTN_STEP(0, bbA0, bbA1, bbB0, bbB1, t)
    ATTN_STEP(1, bbB0, bbB1, bbA0, bbA1, t + 1)
  }
#undef ATTN_STEP

  // epilogue: divide by l, write bf16 [B,NQ,1024]
  float linv = 1.0f / lrun;
#pragma unroll
  for (int j = 0; j < 4; j++) {
    float li = __shfl(linv, g * 4 + j, 64);
    int qq = q0 + w * 16 + g * 4 + j;
#pragma unroll
    for (int d = 0; d < 4; d++)
      Ob[((size_t)b * 2048 + qq) * 1024 + h * 64 + d * 16 + q] =
          f2bf(acc[d][j] * li);
  }
}

// ---------------------------------------------------------------------------
extern "C" void kernel_launch(void* const* d_in, const int* in_sizes, int n_in,
                              void* d_out, int out_size, void* d_ws,
                              size_t ws_size, hipStream_t stream) {
  (void)in_sizes; (void)n_in; (void)out_size;
  const float* q_in = (const float*)d_in[0];
  const float* k_in = (const float*)d_in[1];
  const float* v_in = (const float*)d_in[2];
  const int* mask = (const int*)d_in[3];
  const float* attn_bias = (const float*)d_in[4];
  const float* w_q = (const float*)d_in[5];
  const float* b_q = (const float*)d_in[6];
  const float* w_k = (const float*)d_in[7];
  const float* b_k = (const float*)d_in[8];
  const float* w_v = (const float*)d_in[9];
  const float* b_v = (const float*)d_in[10];
  const float* w_o = (const float*)d_in[11];
  const float* b_o = (const float*)d_in[12];

  const size_t MB = 1u << 20;
  char* ws = (char*)d_ws;
  u16* XQ = (u16*)(ws + 0 * MB);
  u16* XK = (u16*)(ws + 8 * MB);
  u16* XV = (u16*)(ws + 16 * MB);
  u16* WQ = (u16*)(ws + 24 * MB);
  u16* WK = (u16*)(ws + 26 * MB);
  u16* WV = (u16*)(ws + 28 * MB);
  u16* WO = (u16*)(ws + 30 * MB);
  u16* Qb = (u16*)(ws + 32 * MB);
  u16* Kb = (u16*)(ws + 40 * MB);
  u16* Vt = (u16*)(ws + 48 * MB);
  u16* Ob = (u16*)(ws + 56 * MB);
  const bool merged = ws_size >= (size_t)80 * MB;
  u16* BiasE = (u16*)(ws + (merged ? 64 : 0) * MB);

  ConvArgs ca;
  ca.d[0] = {q_in, XQ, 4096 * 1024};
  ca.d[1] = {k_in, XK, 4096 * 1024};
  ca.d[2] = {v_in, XV, 4096 * 1024};
  ca.d[3] = {w_q, WQ, 1024 * 1024};
  ca.d[4] = {w_k, WK, 1024 * 1024};
  ca.d[5] = {w_v, WV, 1024 * 1024};
  ca.d[6] = {w_o, WO, 1024 * 1024};
  k_prep<<<dim3(2048, merged ? 8 : 7), 256, 0, stream>>>(ca, attn_bias, mask,
                                                         BiasE);

  const float QSCALE = 0.125f * 1.44269504f;
  Gemm3 g3;
  g3.d[0] = {XQ, WQ, b_q, (void*)Qb, 0, QSCALE};
  g3.d[1] = {XK, WK, b_k, (void*)Kb, 0, 1.0f};
  g3.d[2] = {XV, WV, b_v, (void*)Vt, 1, 1.0f};
  k_gemm_qkv<<<dim3(8, 32, 3), 256, 0, stream>>>(g3);

  if (!merged) k_biasprep<<<2048, 256, 0, stream>>>(attn_bias, mask, BiasE);

  k_attn<<<dim3(16, 2, 16), 512, 0, stream>>>(Qb, Kb, Vt, BiasE, Ob);

  k_gemm_o<<<dim3(8, 64), 256, 0, stream>>>(Ob, WO, b_o, (float*)d_out);
}

// Round 6
// 152.066 us; speedup vs baseline: 1.7276x; 1.0584x over previous
//
#include <hip/hip_runtime.h>

// ---------------------------------------------------------------------------
// MultiHeadAttention forward, MI355X/gfx950.
// prep(convert+biasmask) -> merged GEMM QKV -> flash attention -> GEMM O
// Round 6: attn KVBLK=128 / 16 steps / ONE barrier per step (drain-old vmcnt),
// bias folded into QK^T MFMA C-in, XCD-grouped grid for K/V L2 locality.
// ---------------------------------------------------------------------------

typedef short bf16x8 __attribute__((ext_vector_type(8)));
typedef short bf16x4 __attribute__((ext_vector_type(4)));
typedef float f32x4 __attribute__((ext_vector_type(4)));
typedef int i32x4 __attribute__((ext_vector_type(4)));
typedef unsigned short u16;
typedef unsigned short u16x8 __attribute__((ext_vector_type(8)));
typedef unsigned short u16x4 __attribute__((ext_vector_type(4)));

#define MFMA16(a, b, c) __builtin_amdgcn_mfma_f32_16x16x32_bf16((a), (b), (c), 0, 0, 0)
#define GLD16(gp, lp)                                                     \
  __builtin_amdgcn_global_load_lds(                                       \
      (const __attribute__((address_space(1))) void*)(gp),                \
      (__attribute__((address_space(3))) void*)(lp), 16, 0, 0)

#define WAITVM_BAR(N) asm volatile("s_waitcnt vmcnt(" #N ")\ns_barrier" ::: "memory")
#define BAR() asm volatile("s_barrier" ::: "memory")

#if __has_builtin(__builtin_amdgcn_exp2f)
#define EXP2(x) __builtin_amdgcn_exp2f(x)
#else
#define EXP2(x) exp2f(x)
#endif

__device__ __forceinline__ f32x4 MFMA_PV(bf16x4 a, bf16x4 b, f32x4 c) {
#if __has_builtin(__builtin_amdgcn_mfma_f32_16x16x16bf16_1k)
  return __builtin_amdgcn_mfma_f32_16x16x16bf16_1k(a, b, c, 0, 0, 0);
#else
  asm("v_mfma_f32_16x16x16_bf16 %0, %1, %2, %0" : "+v"(c) : "v"(a), "v"(b));
  return c;
#endif
}

__device__ __forceinline__ u16 f2bf(float f) {
  union { float f; unsigned u; } v; v.f = f;
  return (u16)((v.u + 0x7fffu + ((v.u >> 16) & 1u)) >> 16);
}
__device__ __forceinline__ unsigned pk2(float x, float y) {
  union { float f; unsigned u; } a, b;
  a.f = x; b.f = y;
  return ((a.u + 0x8000u) >> 16) | ((b.u + 0x8000u) & 0xffff0000u);
}

// ---------------- prep: f32->bf16 convert (y<7) + bias/mask prep (y==7) ----
struct ConvDesc { const float* src; u16* dst; int n; };
struct ConvArgs { ConvDesc d[7]; };

__device__ __forceinline__ void biasprep_body(const float* __restrict__ bias,
                                              const int* __restrict__ mask,
                                              u16* __restrict__ out, int i) {
  const int o0 = i * 16;
  const int rowg = o0 >> 11;
  const int b = rowg >> 11;
  const int off = o0 & 2047;
  const int a = off >> 6, g = (off >> 4) & 3;
  const float* src = bias + (size_t)rowg * 2048 + a * 64 + g * 4;
  const int* msk = mask + b * 2048 + a * 64 + g * 4;
  u16x8 w0 = {}, w1 = {};
#pragma unroll
  for (int c = 0; c < 4; c++) {
    f32x4 v = *(const f32x4*)(src + c * 16);
    i32x4 m = *(const i32x4*)(msk + c * 16);
#pragma unroll
    for (int j = 0; j < 4; j++) {
      u16 val = (m[j] != 0) ? f2bf(v[j] * 1.44269504f) : (u16)0xFF80;
      if (c < 2) w0[c * 4 + j] = val;
      else       w1[(c - 2) * 4 + j] = val;
    }
  }
  *(u16x8*)(out + o0) = w0;
  *(u16x8*)(out + o0 + 8) = w1;
}

__global__ __launch_bounds__(256)
void k_prep(ConvArgs a, const float* __restrict__ bias,
            const int* __restrict__ mask, u16* __restrict__ bout) {
  if (blockIdx.y == 7) {
    biasprep_body(bias, mask, bout, blockIdx.x * 256 + threadIdx.x);
    return;
  }
  ConvDesc cd = a.d[blockIdx.y];
  int i = (blockIdx.x * 256 + threadIdx.x) * 8;
  if (i >= cd.n) return;
  const float4* s = (const float4*)(cd.src + i);
  float4 f0 = s[0], f1 = s[1];
  u16x8 o;
  o[0] = f2bf(f0.x); o[1] = f2bf(f0.y); o[2] = f2bf(f0.z); o[3] = f2bf(f0.w);
  o[4] = f2bf(f1.x); o[5] = f2bf(f1.y); o[6] = f2bf(f1.z); o[7] = f2bf(f1.w);
  *(u16x8*)(cd.dst + i) = o;
}

__global__ __launch_bounds__(256)
void k_biasprep(const float* __restrict__ bias, const int* __restrict__ mask,
                u16* __restrict__ out) {
  biasprep_body(bias, mask, out, blockIdx.x * 256 + threadIdx.x);
}

// ---------------- bf16 GEMM body: C = (A[M,K] * B[N,K]^T + bias)*oscale ----
template <int MF>
__device__ __forceinline__ void gemm_impl(const u16* __restrict__ A,
                                          const u16* __restrict__ Bw,
                                          const float* __restrict__ bias,
                                          void* __restrict__ outp, int mode,
                                          float oscale) {
  __shared__ u16 As[2][MF * 1024];
  __shared__ u16 Bs[2][4096];
  const int tid = threadIdx.x;
  const int lane = tid & 63;
  const int wv = tid >> 6;
  const int wr = wv >> 1, wc = wv & 1;
  const int m0 = blockIdx.y * (MF * 32), n0 = blockIdx.x * 128;

  f32x4 acc[MF][4] = {};

  const int s0 = tid, s1 = 256 + tid;
  const int r0 = s0 >> 2, c0 = (s0 & 3) ^ (r0 & 3);
  const int r1 = s1 >> 2, c1 = (s1 & 3) ^ (r1 & 3);
  const u16* gA0 = A + (size_t)(m0 + r0) * 1024 + c0 * 8;
  const u16* gA1 = A + (size_t)(m0 + r1) * 1024 + c1 * 8;  // MF==4 only
  const u16* gB0 = Bw + (size_t)(n0 + r0) * 1024 + c0 * 8;
  const u16* gB1 = Bw + (size_t)(n0 + r1) * 1024 + c1 * 8;
  u16* lA0 = &As[0][(tid & ~63) * 8];
  u16* lB0 = &Bs[0][(tid & ~63) * 8];

  GLD16(gA0, lA0);
  if constexpr (MF == 4) GLD16(gA1, lA0 + 2048);
  GLD16(gB0, lB0);
  GLD16(gB1, lB0 + 2048);
  WAITVM_BAR(0);

#define GSTEP(BUF, K0)                                                     \
  {                                                                        \
    const int nk = ((K0) + 32) & 1023;                                     \
    GLD16(gA0 + nk, lA0 + ((BUF) ^ 1) * (MF * 1024));                      \
    if constexpr (MF == 4)                                                 \
      GLD16(gA1 + nk, lA0 + 2048 + ((BUF) ^ 1) * (MF * 1024));             \
    GLD16(gB0 + nk, lB0 + ((BUF) ^ 1) * 4096);                             \
    GLD16(gB1 + nk, lB0 + 2048 + ((BUF) ^ 1) * 4096);                      \
    if constexpr (MF == 4) { WAITVM_BAR(4); } else { WAITVM_BAR(3); }      \
    bf16x8 af[MF], bfr[4];                                                 \
    _Pragma("unroll")                                                      \
    for (int mi = 0; mi < MF; mi++) {                                      \
      int row = wr * (MF * 16) + mi * 16 + (lane & 15);                    \
      int byt = row * 64 + (((lane >> 4) * 16) ^ ((row & 3) << 4));        \
      af[mi] = *(const bf16x8*)((const char*)&As[BUF][0] + byt);           \
    }                                                                      \
    _Pragma("unroll")                                                      \
    for (int ni = 0; ni < 4; ni++) {                                       \
      int row = wc * 64 + ni * 16 + (lane & 15);                           \
      int byt = row * 64 + (((lane >> 4) * 16) ^ ((row & 3) << 4));        \
      bfr[ni] = *(const bf16x8*)((const char*)&Bs[BUF][0] + byt);          \
    }                                                                      \
    __builtin_amdgcn_s_setprio(1);                                         \
    _Pragma("unroll")                                                      \
    for (int mi = 0; mi < MF; mi++)                                        \
      _Pragma("unroll")                                                    \
      for (int ni = 0; ni < 4; ni++)                                       \
        acc[mi][ni] = MFMA16(af[mi], bfr[ni], acc[mi][ni]);                \
    __builtin_amdgcn_s_setprio(0);                                         \
    BAR();                                                                 \
  }

  for (int k0 = 0; k0 < 1024; k0 += 64) {
    GSTEP(0, k0)
    GSTEP(1, k0 + 32)
  }
#undef GSTEP

#pragma unroll
  for (int ni = 0; ni < 4; ni++) {
    int n = n0 + wc * 64 + ni * 16 + (lane & 15);
    float bv = bias[n];
#pragma unroll
    for (int mi = 0; mi < MF; mi++) {
      int mb = m0 + wr * (MF * 16) + mi * 16 + (lane >> 4) * 4;
      if (mode == 2) {
        float* O = (float*)outp;
#pragma unroll
        for (int r = 0; r < 4; r++)
          O[(size_t)(mb + r) * 1024 + n] = (acc[mi][ni][r] + bv) * oscale;
      } else if (mode == 0) {
        u16* O = (u16*)outp;
        int b = mb >> 11, q = mb & 2047;
        int h = n >> 6, dk = n & 63;
        size_t base = ((size_t)(b * 16 + h) * 2048 + q) * 64 + dk;
#pragma unroll
        for (int r = 0; r < 4; r++)
          O[base + (size_t)r * 64] = f2bf((acc[mi][ni][r] + bv) * oscale);
      } else {  // mode 1: V^T [B,H,64,NK]
        u16* O = (u16*)outp;
        int b = mb >> 11, kv = mb & 2047;
        int h = n >> 6, dk = n & 63;
        u16x4 pk;
#pragma unroll
        for (int r = 0; r < 4; r++) pk[r] = f2bf((acc[mi][ni][r] + bv) * oscale);
        *(u16x4*)((u16*)O + ((size_t)((b * 16 + h) * 64 + dk)) * 2048 + kv) = pk;
      }
    }
  }
}

struct GemmDesc { const u16* A; const u16* W; const float* bias; void* out;
                  int mode; float oscale; };
struct Gemm3 { GemmDesc d[3]; };

__global__ __launch_bounds__(256, 2) void k_gemm_qkv(Gemm3 g3) {
  GemmDesc gd = g3.d[blockIdx.z];
  gemm_impl<4>(gd.A, gd.W, gd.bias, gd.out, gd.mode, gd.oscale);
}
__global__ __launch_bounds__(256, 2)
void k_gemm_o(const u16* __restrict__ A, const u16* __restrict__ W,
              const float* __restrict__ bias, float* __restrict__ out) {
  gemm_impl<2>(A, W, bias, out, 2, 1.0f);
}

// ---------------- flash attention, KVBLK=128, 512 thr / 8 waves ------------
// 1-D grid 512, XCD-grouped: xcd=bid&7 owns 4 (b,h) pairs, all 16 q-tiles of
// a pair co-resident on one XCD (K/V served from its L2). One barrier/step:
// step = {waitvm(0)+bar, QK^T (bias as MFMA C-in), issue next K/V/bias,
// softmax, PV}. Loads fly across softmax+PV of their issue step.
__global__ __launch_bounds__(512, 4)
void k_attn(const u16* __restrict__ Qb, const u16* __restrict__ Kb,
            const u16* __restrict__ Vt, const u16* __restrict__ BiasE,
            u16* __restrict__ Ob) {
  __shared__ u16 Ks[2][128 * 64];
  __shared__ u16 Vs[2][64 * 128];

  const int tid = threadIdx.x, lane = tid & 63, w = tid >> 6;
  const int g = lane >> 4, q = lane & 15;
  const int bid = blockIdx.x;
  const int xcd = bid & 7, rr = bid >> 3;
  const int qt = rr & 15;
  const int pr = xcd + 8 * (rr >> 4);   // (b,h) pair, 4 per XCD
  const int b = pr >> 4, h = pr & 15;
  const int q0 = qt * 128;
  const size_t bh = (size_t)(b * 16 + h);

  // Q as B-operand (prescaled by 0.125*log2e at projection)
  const u16* Qrow = Qb + (bh * 2048 + q0 + w * 16 + q) * 64;
  bf16x8 bq0 = *(const bf16x8*)(Qrow + g * 8);
  bf16x8 bq1 = *(const bf16x8*)(Qrow + 32 + g * 8);

  f32x4 acc[4] = {};
  float mrun = -1e30f, lrun = 0.f;

  // K staging: 1024 slots of 16B = 128 rows x 8 chunks, chunk xor (row&7)
  const int sK1 = tid + 512;
  const int rK0 = tid >> 3, cK0 = (tid & 7) ^ (rK0 & 7);
  const int rK1 = sK1 >> 3, cK1 = (sK1 & 7) ^ (rK1 & 7);
  // V staging: 64 rows x 16 chunks of 16B, chunk xor (row&7) on low 3 bits
  const int rV0 = tid >> 4, cV0 = (tid & 15) ^ (rV0 & 7);
  const int rV1 = sK1 >> 4, cV1 = (sK1 & 15) ^ (rV1 & 7);
  const u16* Kg = Kb + bh * 2048 * 64;
  const u16* Vg = Vt + bh * 64 * 2048;
  const int ld0 = (tid & ~63) * 8, ld1 = ld0 + 4096;

  const u16* brow = BiasE + ((size_t)b * 2048 + q0 + w * 16 + q) * 2048 + g * 16;

  // prologue: stage tile 0 + bias tile 0
  GLD16(Kg + (size_t)rK0 * 64 + cK0 * 8, &Ks[0][ld0]);
  GLD16(Kg + (size_t)rK1 * 64 + cK1 * 8, &Ks[0][ld1]);
  GLD16(Vg + (size_t)rV0 * 2048 + cV0 * 8, &Vs[0][ld0]);
  GLD16(Vg + (size_t)rV1 * 2048 + cV1 * 8, &Vs[0][ld1]);
  u16x8 bb0 = *(const u16x8*)(brow);
  u16x8 bb1 = *(const u16x8*)(brow + 8);
  u16x8 bb2 = *(const u16x8*)(brow + 64);
  u16x8 bb3 = *(const u16x8*)(brow + 72);

#define ATTN_STEP(BUF, T)                                                      \
  {                                                                            \
    WAITVM_BAR(0); /* drains prev-step loads (issued ~1 step ago) */           \
    f32x4 sc[8];                                                               \
    __builtin_amdgcn_s_setprio(1);                                             \
    _Pragma("unroll")                                                          \
    for (int c = 0; c < 8; c++) {                                              \
      const int kvr = c * 16 + q;                                              \
      bf16x8 ak0 = *(const bf16x8*)((const char*)&Ks[BUF][0] + kvr * 128 +     \
                                    ((g * 16) ^ ((kvr & 7) << 4)));            \
      bf16x8 ak1 = *(const bf16x8*)((const char*)&Ks[BUF][0] + kvr * 128 +     \
                                    ((64 + g * 16) ^ ((kvr & 7) << 4)));       \
      const u16x8 blo = (c & 4) ? bb2 : bb0;                                   \
      const u16x8 bhi = (c & 4) ? bb3 : bb1;                                   \
      f32x4 cin;                                                               \
      _Pragma("unroll")                                                        \
      for (int r = 0; r < 4; r++) {                                            \
        unsigned braw = (unsigned)(((c & 3) < 2)                               \
                                       ? blo[(c & 3) * 4 + r]                  \
                                       : bhi[((c & 3) - 2) * 4 + r]);          \
        cin[r] = __uint_as_float(braw << 16);                                  \
      }                                                                        \
      f32x4 z = MFMA16(ak0, bq0, cin);                                         \
      sc[c] = MFMA16(ak1, bq1, z);                                             \
    }                                                                          \
    __builtin_amdgcn_s_setprio(0);                                             \
    const int nkv = (((T) + 1) & 15) * 128;                                    \
    GLD16(Kg + (size_t)(nkv + rK0) * 64 + cK0 * 8, &Ks[(BUF) ^ 1][ld0]);       \
    GLD16(Kg + (size_t)(nkv + rK1) * 64 + cK1 * 8, &Ks[(BUF) ^ 1][ld1]);       \
    GLD16(Vg + (size_t)rV0 * 2048 + nkv + cV0 * 8, &Vs[(BUF) ^ 1][ld0]);       \
    GLD16(Vg + (size_t)rV1 * 2048 + nkv + cV1 * 8, &Vs[(BUF) ^ 1][ld1]);       \
    bb0 = *(const u16x8*)(brow + nkv);                                         \
    bb1 = *(const u16x8*)(brow + nkv + 8);                                     \
    bb2 = *(const u16x8*)(brow + nkv + 64);                                    \
    bb3 = *(const u16x8*)(brow + nkv + 72);                                    \
    float tmax = -3e38f;                                                       \
    _Pragma("unroll")                                                          \
    for (int c = 0; c < 8; c++)                                                \
      _Pragma("unroll")                                                        \
      for (int r = 0; r < 4; r++) tmax = fmaxf(tmax, sc[c][r]);                \
    tmax = fmaxf(tmax, __shfl_xor(tmax, 16, 64));                              \
    tmax = fmaxf(tmax, __shfl_xor(tmax, 32, 64));                              \
    if (__any(tmax > mrun)) {                                                  \
      float mnew = fmaxf(mrun, tmax);                                          \
      float alpha = EXP2(mrun - mnew);                                         \
      mrun = mnew;                                                             \
      lrun *= alpha;                                                           \
      _Pragma("unroll")                                                        \
      for (int j = 0; j < 4; j++) {                                            \
        float aj = __shfl(alpha, g * 4 + j, 64);                               \
        _Pragma("unroll")                                                      \
        for (int d = 0; d < 4; d++) acc[d][j] *= aj;                           \
      }                                                                        \
    }                                                                          \
    float rsum = 0.f;                                                          \
    float pp[8][4];                                                            \
    _Pragma("unroll")                                                          \
    for (int c = 0; c < 8; c++)                                                \
      _Pragma("unroll")                                                        \
      for (int r = 0; r < 4; r++) {                                            \
        pp[c][r] = EXP2(sc[c][r] - mrun);                                      \
        rsum += pp[c][r];                                                      \
      }                                                                        \
    rsum += __shfl_xor(rsum, 16, 64);                                          \
    rsum += __shfl_xor(rsum, 32, 64);                                          \
    lrun += rsum;                                                              \
    __builtin_amdgcn_s_setprio(1);                                             \
    _Pragma("unroll")                                                          \
    for (int c = 0; c < 8; c++) {                                              \
      union { unsigned u[2]; bf16x4 v; } pa;                                   \
      pa.u[0] = pk2(pp[c][0], pp[c][1]);                                       \
      pa.u[1] = pk2(pp[c][2], pp[c][3]);                                       \
      _Pragma("unroll")                                                        \
      for (int d = 0; d < 4; d++) {                                            \
        const int dr = d * 16 + q;                                             \
        bf16x4 vb = *(const bf16x4*)((const char*)&Vs[BUF][0] + dr * 256 +     \
                                     ((c * 32 + g * 8) ^ ((dr & 7) << 4)));    \
        acc[d] = MFMA_PV(pa.v, vb, acc[d]);                                    \
      }                                                                        \
    }                                                                          \
    __builtin_amdgcn_s_setprio(0);                                             \
  }

  for (int t = 0; t < 16; t += 2) {
    ATTN_STEP(0, t)
    ATTN_STEP(1, t + 1)
  }
#undef ATTN_STEP

  // epilogue: divide by l, write bf16 [B,NQ,1024]
  float linv = 1.0f / lrun;
#pragma unroll
  for (int j = 0; j < 4; j++) {
    float li = __shfl(linv, g * 4 + j, 64);
    int qq = q0 + w * 16 + g * 4 + j;
#pragma unroll
    for (int d = 0; d < 4; d++)
      Ob[((size_t)b * 2048 + qq) * 1024 + h * 64 + d * 16 + q] =
          f2bf(acc[d][j] * li);
  }
}

// ---------------------------------------------------------------------------
extern "C" void kernel_launch(void* const* d_in, const int* in_sizes, int n_in,
                              void* d_out, int out_size, void* d_ws,
                              size_t ws_size, hipStream_t stream) {
  (void)in_sizes; (void)n_in; (void)out_size;
  const float* q_in = (const float*)d_in[0];
  const float* k_in = (const float*)d_in[1];
  const float* v_in = (const float*)d_in[2];
  const int* mask = (const int*)d_in[3];
  const float* attn_bias = (const float*)d_in[4];
  const float* w_q = (const float*)d_in[5];
  const float* b_q = (const float*)d_in[6];
  const float* w_k = (const float*)d_in[7];
  const float* b_k = (const float*)d_in[8];
  const float* w_v = (const float*)d_in[9];
  const float* b_v = (const float*)d_in[10];
  const float* w_o = (const float*)d_in[11];
  const float* b_o = (const float*)d_in[12];

  const size_t MB = 1u << 20;
  char* ws = (char*)d_ws;
  u16* XQ = (u16*)(ws + 0 * MB);
  u16* XK = (u16*)(ws + 8 * MB);
  u16* XV = (u16*)(ws + 16 * MB);
  u16* WQ = (u16*)(ws + 24 * MB);
  u16* WK = (u16*)(ws + 26 * MB);
  u16* WV = (u16*)(ws + 28 * MB);
  u16* WO = (u16*)(ws + 30 * MB);
  u16* Qb = (u16*)(ws + 32 * MB);
  u16* Kb = (u16*)(ws + 40 * MB);
  u16* Vt = (u16*)(ws + 48 * MB);
  u16* Ob = (u16*)(ws + 56 * MB);
  const bool merged = ws_size >= (size_t)80 * MB;
  u16* BiasE = (u16*)(ws + (merged ? 64 : 0) * MB);

  ConvArgs ca;
  ca.d[0] = {q_in, XQ, 4096 * 1024};
  ca.d[1] = {k_in, XK, 4096 * 1024};
  ca.d[2] = {v_in, XV, 4096 * 1024};
  ca.d[3] = {w_q, WQ, 1024 * 1024};
  ca.d[4] = {w_k, WK, 1024 * 1024};
  ca.d[5] = {w_v, WV, 1024 * 1024};
  ca.d[6] = {w_o, WO, 1024 * 1024};
  k_prep<<<dim3(2048, merged ? 8 : 7), 256, 0, stream>>>(ca, attn_bias, mask,
                                                         BiasE);

  const float QSCALE = 0.125f * 1.44269504f;
  Gemm3 g3;
  g3.d[0] = {XQ, WQ, b_q, (void*)Qb, 0, QSCALE};
  g3.d[1] = {XK, WK, b_k, (void*)Kb, 0, 1.0f};
  g3.d[2] = {XV, WV, b_v, (void*)Vt, 1, 1.0f};
  k_gemm_qkv<<<dim3(8, 32, 3), 256, 0, stream>>>(g3);

  if (!merged) k_biasprep<<<2048, 256, 0, stream>>>(attn_bias, mask, BiasE);

  k_attn<<<512, 512, 0, stream>>>(Qb, Kb, Vt, BiasE, Ob);

  k_gemm_o<<<dim3(8, 64), 256, 0, stream>>>(Ob, WO, b_o, (float*)d_out);
}

// Round 7
// 149.260 us; speedup vs baseline: 1.7601x; 1.0188x over previous
//
#include <hip/hip_runtime.h>

// ---------------------------------------------------------------------------
// MultiHeadAttention forward, MI355X/gfx950.
// prep(convert+biasmask) -> merged GEMM QKV -> flash attention -> GEMM O
// Round 7: attn on mfma_32x32x16 (wave owns 32 q): LDS traffic per work
// halved, lane-local softmax state (1 shuffle/reduce, 0-shuffle rescale),
// in-register P via pk2+v_permlane32_swap_b32 (T12).
// ---------------------------------------------------------------------------

typedef short bf16x8 __attribute__((ext_vector_type(8)));
typedef short bf16x4 __attribute__((ext_vector_type(4)));
typedef float f32x4 __attribute__((ext_vector_type(4)));
typedef float f32x16 __attribute__((ext_vector_type(16)));
typedef int i32x4 __attribute__((ext_vector_type(4)));
typedef unsigned short u16;
typedef unsigned short u16x8 __attribute__((ext_vector_type(8)));
typedef unsigned short u16x4 __attribute__((ext_vector_type(4)));

#define MFMA16(a, b, c) __builtin_amdgcn_mfma_f32_16x16x32_bf16((a), (b), (c), 0, 0, 0)
#define MFMA32(a, b, c) __builtin_amdgcn_mfma_f32_32x32x16_bf16((a), (b), (c), 0, 0, 0)
#define GLD16(gp, lp)                                                     \
  __builtin_amdgcn_global_load_lds(                                       \
      (const __attribute__((address_space(1))) void*)(gp),                \
      (__attribute__((address_space(3))) void*)(lp), 16, 0, 0)

#define WAITVM_BAR(N) asm volatile("s_waitcnt vmcnt(" #N ")\ns_barrier" ::: "memory")
#define BAR() asm volatile("s_barrier" ::: "memory")

#if __has_builtin(__builtin_amdgcn_exp2f)
#define EXP2(x) __builtin_amdgcn_exp2f(x)
#else
#define EXP2(x) exp2f(x)
#endif

__device__ __forceinline__ u16 f2bf(float f) {
  union { float f; unsigned u; } v; v.f = f;
  return (u16)((v.u + 0x7fffu + ((v.u >> 16) & 1u)) >> 16);
}
__device__ __forceinline__ unsigned pk2(float x, float y) {
  union { float f; unsigned u; } a, b;
  a.f = x; b.f = y;
  return ((a.u + 0x8000u) >> 16) | ((b.u + 0x8000u) & 0xffff0000u);
}
// swap: a' = [a.lo32lanes, b.lo32lanes], b' = [a.hi, b.hi]
__device__ __forceinline__ void pl32swap(unsigned& a, unsigned& b) {
  asm("v_permlane32_swap_b32 %0, %1" : "+v"(a), "+v"(b));
}

// ---------------- prep: f32->bf16 convert (y<7) + bias/mask prep (y==7) ----
struct ConvDesc { const float* src; u16* dst; int n; };
struct ConvArgs { ConvDesc d[7]; };

// bias_eff layout for the 32x32 fragment: out[b][q][c*32 + hi*16 + r]
//   = mask ? bias[b][q][c*32 + (r&3) + 8*(r>>2) + 4*hi] * log2e : -inf
__device__ __forceinline__ void biasprep_body(const float* __restrict__ bias,
                                              const int* __restrict__ mask,
                                              u16* __restrict__ out, int i) {
  const int o0 = i * 16;
  const int rowg = o0 >> 11;       // b*2048 + q
  const int b = rowg >> 11;
  const int off = o0 & 2047;
  const int c = off >> 5;          // 32-kv block
  const int hi = (off >> 4) & 1;
  const float* src = bias + (size_t)rowg * 2048 + c * 32 + hi * 4;
  const int* msk = mask + b * 2048 + c * 32 + hi * 4;
  u16x8 w0 = {}, w1 = {};
#pragma unroll
  for (int t = 0; t < 4; t++) {
    f32x4 v = *(const f32x4*)(src + t * 8);
    i32x4 m = *(const i32x4*)(msk + t * 8);
#pragma unroll
    for (int j = 0; j < 4; j++) {
      u16 val = (m[j] != 0) ? f2bf(v[j] * 1.44269504f) : (u16)0xFF80;
      if (t < 2) w0[t * 4 + j] = val;
      else       w1[(t - 2) * 4 + j] = val;
    }
  }
  *(u16x8*)(out + o0) = w0;
  *(u16x8*)(out + o0 + 8) = w1;
}

__global__ __launch_bounds__(256)
void k_prep(ConvArgs a, const float* __restrict__ bias,
            const int* __restrict__ mask, u16* __restrict__ bout) {
  if (blockIdx.y == 7) {
    biasprep_body(bias, mask, bout, blockIdx.x * 256 + threadIdx.x);
    return;
  }
  ConvDesc cd = a.d[blockIdx.y];
  int i = (blockIdx.x * 256 + threadIdx.x) * 8;
  if (i >= cd.n) return;
  const float4* s = (const float4*)(cd.src + i);
  float4 f0 = s[0], f1 = s[1];
  u16x8 o;
  o[0] = f2bf(f0.x); o[1] = f2bf(f0.y); o[2] = f2bf(f0.z); o[3] = f2bf(f0.w);
  o[4] = f2bf(f1.x); o[5] = f2bf(f1.y); o[6] = f2bf(f1.z); o[7] = f2bf(f1.w);
  *(u16x8*)(cd.dst + i) = o;
}

__global__ __launch_bounds__(256)
void k_biasprep(const float* __restrict__ bias, const int* __restrict__ mask,
                u16* __restrict__ out) {
  biasprep_body(bias, mask, out, blockIdx.x * 256 + threadIdx.x);
}

// ---------------- bf16 GEMM body: C = (A[M,K] * B[N,K]^T + bias)*oscale ----
template <int MF>
__device__ __forceinline__ void gemm_impl(const u16* __restrict__ A,
                                          const u16* __restrict__ Bw,
                                          const float* __restrict__ bias,
                                          void* __restrict__ outp, int mode,
                                          float oscale) {
  __shared__ u16 As[2][MF * 1024];
  __shared__ u16 Bs[2][4096];
  const int tid = threadIdx.x;
  const int lane = tid & 63;
  const int wv = tid >> 6;
  const int wr = wv >> 1, wc = wv & 1;
  const int m0 = blockIdx.y * (MF * 32), n0 = blockIdx.x * 128;

  f32x4 acc[MF][4] = {};

  const int s0 = tid, s1 = 256 + tid;
  const int r0 = s0 >> 2, c0 = (s0 & 3) ^ (r0 & 3);
  const int r1 = s1 >> 2, c1 = (s1 & 3) ^ (r1 & 3);
  const u16* gA0 = A + (size_t)(m0 + r0) * 1024 + c0 * 8;
  const u16* gA1 = A + (size_t)(m0 + r1) * 1024 + c1 * 8;  // MF==4 only
  const u16* gB0 = Bw + (size_t)(n0 + r0) * 1024 + c0 * 8;
  const u16* gB1 = Bw + (size_t)(n0 + r1) * 1024 + c1 * 8;
  u16* lA0 = &As[0][(tid & ~63) * 8];
  u16* lB0 = &Bs[0][(tid & ~63) * 8];

  GLD16(gA0, lA0);
  if constexpr (MF == 4) GLD16(gA1, lA0 + 2048);
  GLD16(gB0, lB0);
  GLD16(gB1, lB0 + 2048);
  WAITVM_BAR(0);

#define GSTEP(BUF, K0)                                                     \
  {                                                                        \
    const int nk = ((K0) + 32) & 1023;                                     \
    GLD16(gA0 + nk, lA0 + ((BUF) ^ 1) * (MF * 1024));                      \
    if constexpr (MF == 4)                                                 \
      GLD16(gA1 + nk, lA0 + 2048 + ((BUF) ^ 1) * (MF * 1024));             \
    GLD16(gB0 + nk, lB0 + ((BUF) ^ 1) * 4096);                             \
    GLD16(gB1 + nk, lB0 + 2048 + ((BUF) ^ 1) * 4096);                      \
    if constexpr (MF == 4) { WAITVM_BAR(4); } else { WAITVM_BAR(3); }      \
    bf16x8 af[MF], bfr[4];                                                 \
    _Pragma("unroll")                                                      \
    for (int mi = 0; mi < MF; mi++) {                                      \
      int row = wr * (MF * 16) + mi * 16 + (lane & 15);                    \
      int byt = row * 64 + (((lane >> 4) * 16) ^ ((row & 3) << 4));        \
      af[mi] = *(const bf16x8*)((const char*)&As[BUF][0] + byt);           \
    }                                                                      \
    _Pragma("unroll")                                                      \
    for (int ni = 0; ni < 4; ni++) {                                       \
      int row = wc * 64 + ni * 16 + (lane & 15);                           \
      int byt = row * 64 + (((lane >> 4) * 16) ^ ((row & 3) << 4));        \
      bfr[ni] = *(const bf16x8*)((const char*)&Bs[BUF][0] + byt);          \
    }                                                                      \
    __builtin_amdgcn_s_setprio(1);                                         \
    _Pragma("unroll")                                                      \
    for (int mi = 0; mi < MF; mi++)                                        \
      _Pragma("unroll")                                                    \
      for (int ni = 0; ni < 4; ni++)                                       \
        acc[mi][ni] = MFMA16(af[mi], bfr[ni], acc[mi][ni]);                \
    __builtin_amdgcn_s_setprio(0);                                         \
    BAR();                                                                 \
  }

  for (int k0 = 0; k0 < 1024; k0 += 64) {
    GSTEP(0, k0)
    GSTEP(1, k0 + 32)
  }
#undef GSTEP

#pragma unroll
  for (int ni = 0; ni < 4; ni++) {
    int n = n0 + wc * 64 + ni * 16 + (lane & 15);
    float bv = bias[n];
#pragma unroll
    for (int mi = 0; mi < MF; mi++) {
      int mb = m0 + wr * (MF * 16) + mi * 16 + (lane >> 4) * 4;
      if (mode == 2) {
        float* O = (float*)outp;
#pragma unroll
        for (int r = 0; r < 4; r++)
          O[(size_t)(mb + r) * 1024 + n] = (acc[mi][ni][r] + bv) * oscale;
      } else if (mode == 0) {
        u16* O = (u16*)outp;
        int b = mb >> 11, q = mb & 2047;
        int h = n >> 6, dk = n & 63;
        size_t base = ((size_t)(b * 16 + h) * 2048 + q) * 64 + dk;
#pragma unroll
        for (int r = 0; r < 4; r++)
          O[base + (size_t)r * 64] = f2bf((acc[mi][ni][r] + bv) * oscale);
      } else {  // mode 1: V^T [B,H,64,NK]
        u16* O = (u16*)outp;
        int b = mb >> 11, kv = mb & 2047;
        int h = n >> 6, dk = n & 63;
        u16x4 pk;
#pragma unroll
        for (int r = 0; r < 4; r++) pk[r] = f2bf((acc[mi][ni][r] + bv) * oscale);
        *(u16x4*)((u16*)O + ((size_t)((b * 16 + h) * 64 + dk)) * 2048 + kv) = pk;
      }
    }
  }
}

struct GemmDesc { const u16* A; const u16* W; const float* bias; void* out;
                  int mode; float oscale; };
struct Gemm3 { GemmDesc d[3]; };

__global__ __launch_bounds__(256, 2) void k_gemm_qkv(Gemm3 g3) {
  GemmDesc gd = g3.d[blockIdx.z];
  gemm_impl<4>(gd.A, gd.W, gd.bias, gd.out, gd.mode, gd.oscale);
}
__global__ __launch_bounds__(256, 2)
void k_gemm_o(const u16* __restrict__ A, const u16* __restrict__ W,
              const float* __restrict__ bias, float* __restrict__ out) {
  gemm_impl<2>(A, W, bias, out, 2, 1.0f);
}

// ---------------- flash attention, 32x32 MFMA, KVBLK=128, 256 thr ----------
// 512 blocks (XCD-grouped), 4 waves; wave owns 32 q rows. S^T = K.Q^T via
// mfma_32x32x16 (A=K frag from LDS, B=Q frag in regs, C=premasked bias).
// D layout col=lane&31=q -> softmax state lane-local (1 shfl_xor(32) per
// reduce, rescale shuffle-free). P^T built in-register: pk2 + permlane32_swap.
__global__ __launch_bounds__(256, 2)
void k_attn(const u16* __restrict__ Qb, const u16* __restrict__ Kb,
            const u16* __restrict__ Vt, const u16* __restrict__ BiasE,
            u16* __restrict__ Ob) {
  __shared__ u16 Ks[2][128 * 64];
  __shared__ u16 Vs[2][64 * 128];

  const int tid = threadIdx.x, lane = tid & 63, w = tid >> 6;
  const int l31 = lane & 31, hi2 = lane >> 5;
  const int bid = blockIdx.x;
  const int xcd = bid & 7, rr = bid >> 3;
  const int qt = rr & 15;
  const int pr = xcd + 8 * (rr >> 4);   // (b,h) pair, 4 per XCD
  const int b = pr >> 4, h = pr & 15;
  const int q0 = qt * 128;
  const size_t bh = (size_t)(b * 16 + h);

  // Q as B-operand of 32x32x16: col=q(l31), k=hi2*8+j, one frag per d-chunk
  const u16* Qrow = Qb + (bh * 2048 + q0 + w * 32 + l31) * 64 + hi2 * 8;
  bf16x8 bq[4];
#pragma unroll
  for (int dc = 0; dc < 4; dc++) bq[dc] = *(const bf16x8*)(Qrow + dc * 16);

  f32x16 acc[2] = {};   // O^T: q=l31, d=(r&3)+8*(r>>2)+4*hi2+32*ds
  float mrun = -1e30f, lrun = 0.f;

  // staging maps (4 x GLD16 each for K and V per thread)
  const u16* Kg = Kb + bh * 2048 * 64;
  const u16* Vg = Vt + bh * 64 * 2048;
  int rK[4], cK[4], rV[4], cV[4], ldd[4];
#pragma unroll
  for (int i = 0; i < 4; i++) {
    int s = i * 256 + tid;
    rK[i] = s >> 3; cK[i] = (s & 7) ^ (rK[i] & 7);      // 128 rows x 8 chunks
    rV[i] = s >> 4; cV[i] = (s & 15) ^ (rV[i] & 7);     // 64 rows x 16 chunks
    ldd[i] = (i * 256 + (tid & ~63)) * 8;
  }
  const int kx = (lane & 7) << 4;  // row&7 == lane&7 for all our LDS reads

  const u16* brow =
      BiasE + ((size_t)b * 2048 + q0 + w * 32 + l31) * 2048 + hi2 * 16;

  // prologue: stage tile 0 + bias 0
#pragma unroll
  for (int i = 0; i < 4; i++)
    GLD16(Kg + (size_t)rK[i] * 64 + cK[i] * 8, &Ks[0][ldd[i]]);
#pragma unroll
  for (int i = 0; i < 4; i++)
    GLD16(Vg + (size_t)rV[i] * 2048 + cV[i] * 8, &Vs[0][ldd[i]]);
  u16x8 bb[4][2];
#pragma unroll
  for (int c = 0; c < 4; c++) {
    bb[c][0] = *(const u16x8*)(brow + c * 32);
    bb[c][1] = *(const u16x8*)(brow + c * 32 + 8);
  }

#define ATTN_STEP(BUF, T)                                                      \
  {                                                                            \
    WAITVM_BAR(0); /* drains prev-step loads (issued ~1 step ago) */           \
    const char* kb = (const char*)&Ks[BUF][0];                                 \
    const char* vb = (const char*)&Vs[BUF][0];                                 \
    f32x16 sc[4];                                                              \
    __builtin_amdgcn_s_setprio(1);                                             \
    _Pragma("unroll")                                                          \
    for (int c = 0; c < 4; c++) {                                              \
      f32x16 z;                                                                \
      _Pragma("unroll")                                                        \
      for (int r = 0; r < 8; r++)                                              \
        z[r] = __uint_as_float((unsigned)bb[c][0][r] << 16);                   \
      _Pragma("unroll")                                                        \
      for (int r = 0; r < 8; r++)                                              \
        z[8 + r] = __uint_as_float((unsigned)bb[c][1][r] << 16);               \
      const int rowb = (c * 32 + l31) * 128;                                   \
      _Pragma("unroll")                                                        \
      for (int dc = 0; dc < 4; dc++) {                                         \
        bf16x8 ak =                                                            \
            *(const bf16x8*)(kb + rowb + ((dc * 32 + hi2 * 16) ^ kx));         \
        z = MFMA32(ak, bq[dc], z);                                             \
      }                                                                        \
      sc[c] = z;                                                               \
    }                                                                          \
    __builtin_amdgcn_s_setprio(0);                                             \
    const int nkv = (((T) + 1) & 15) * 128;                                    \
    _Pragma("unroll")                                                          \
    for (int i = 0; i < 4; i++)                                                \
      GLD16(Kg + (size_t)(nkv + rK[i]) * 64 + cK[i] * 8,                       \
            &Ks[(BUF) ^ 1][ldd[i]]);                                           \
    _Pragma("unroll")                                                          \
    for (int i = 0; i < 4; i++)                                                \
      GLD16(Vg + (size_t)rV[i] * 2048 + nkv + cV[i] * 8,                       \
            &Vs[(BUF) ^ 1][ldd[i]]);                                           \
    _Pragma("unroll")                                                          \
    for (int c = 0; c < 4; c++) {                                              \
      bb[c][0] = *(const u16x8*)(brow + nkv + c * 32);                         \
      bb[c][1] = *(const u16x8*)(brow + nkv + c * 32 + 8);                     \
    }                                                                          \
    float tmax = -3e38f;                                                       \
    _Pragma("unroll")                                                          \
    for (int c = 0; c < 4; c++)                                                \
      _Pragma("unroll")                                                        \
      for (int r = 0; r < 16; r++) tmax = fmaxf(tmax, sc[c][r]);               \
    tmax = fmaxf(tmax, __shfl_xor(tmax, 32, 64));                              \
    if (__any(tmax > mrun)) {                                                  \
      float mnew = fmaxf(mrun, tmax);                                          \
      float alpha = EXP2(mrun - mnew);                                         \
      mrun = mnew;                                                             \
      lrun *= alpha;                                                           \
      _Pragma("unroll")                                                        \
      for (int ds = 0; ds < 2; ds++)                                           \
        _Pragma("unroll")                                                      \
        for (int r = 0; r < 16; r++) acc[ds][r] *= alpha;                      \
    }                                                                          \
    float rsum = 0.f;                                                          \
    _Pragma("unroll")                                                          \
    for (int c = 0; c < 4; c++)                                                \
      _Pragma("unroll")                                                        \
      for (int r = 0; r < 16; r++) {                                           \
        sc[c][r] = EXP2(sc[c][r] - mrun);                                      \
        rsum += sc[c][r];                                                      \
      }                                                                        \
    rsum += __shfl_xor(rsum, 32, 64);                                          \
    lrun += rsum;                                                              \
    __builtin_amdgcn_s_setprio(1);                                             \
    _Pragma("unroll")                                                          \
    for (int c = 0; c < 4; c++) {                                              \
      unsigned a0 = pk2(sc[c][0], sc[c][1]), b0 = pk2(sc[c][4], sc[c][5]);     \
      unsigned a1 = pk2(sc[c][2], sc[c][3]), b1 = pk2(sc[c][6], sc[c][7]);     \
      unsigned e0 = pk2(sc[c][8], sc[c][9]), f0 = pk2(sc[c][12], sc[c][13]);   \
      unsigned e1 = pk2(sc[c][10], sc[c][11]), f1 = pk2(sc[c][14], sc[c][15]); \
      pl32swap(a0, b0); pl32swap(a1, b1);                                      \
      pl32swap(e0, f0); pl32swap(e1, f1);                                      \
      union { unsigned u[4]; bf16x8 v; } fe, fo;                               \
      fe.u[0] = a0; fe.u[1] = a1; fe.u[2] = b0; fe.u[3] = b1;                  \
      fo.u[0] = e0; fo.u[1] = e1; fo.u[2] = f0; fo.u[3] = f1;                  \
      _Pragma("unroll")                                                        \
      for (int ds = 0; ds < 2; ds++) {                                         \
        const int vrow = (ds * 32 + l31) * 256;                                \
        bf16x8 ve =                                                            \
            *(const bf16x8*)(vb + vrow + (((c * 4 + hi2) * 16) ^ kx));         \
        acc[ds] = MFMA32(ve, fe.v, acc[ds]);                                   \
        bf16x8 vo =                                                            \
            *(const bf16x8*)(vb + vrow + (((c * 4 + 2 + hi2) * 16) ^ kx));     \
        acc[ds] = MFMA32(vo, fo.v, acc[ds]);                                   \
      }                                                                        \
    }                                                                          \
    __builtin_amdgcn_s_setprio(0);                                             \
  }

  for (int t = 0; t < 16; t += 2) {
    ATTN_STEP(0, t)
    ATTN_STEP(1, t + 1)
  }
#undef ATTN_STEP

  // epilogue: O/l, write bf16 [B,NQ,1024]; q = l31 (lane-local l)
  float linv = 1.0f / lrun;
  const size_t obase =
      ((size_t)b * 2048 + q0 + w * 32 + l31) * 1024 + h * 64 + hi2 * 4;
#pragma unroll
  for (int ds = 0; ds < 2; ds++)
#pragma unroll
    for (int t = 0; t < 4; t++) {
      u16x4 pk;
#pragma unroll
      for (int j = 0; j < 4; j++) pk[j] = f2bf(acc[ds][t * 4 + j] * linv);
      *(u16x4*)(Ob + obase + ds * 32 + t * 8) = pk;
    }
}

// ---------------------------------------------------------------------------
extern "C" void kernel_launch(void* const* d_in, const int* in_sizes, int n_in,
                              void* d_out, int out_size, void* d_ws,
                              size_t ws_size, hipStream_t stream) {
  (void)in_sizes; (void)n_in; (void)out_size;
  const float* q_in = (const float*)d_in[0];
  const float* k_in = (const float*)d_in[1];
  const float* v_in = (const float*)d_in[2];
  const int* mask = (const int*)d_in[3];
  const float* attn_bias = (const float*)d_in[4];
  const float* w_q = (const float*)d_in[5];
  const float* b_q = (const float*)d_in[6];
  const float* w_k = (const float*)d_in[7];
  const float* b_k = (const float*)d_in[8];
  const float* w_v = (const float*)d_in[9];
  const float* b_v = (const float*)d_in[10];
  const float* w_o = (const float*)d_in[11];
  const float* b_o = (const float*)d_in[12];

  const size_t MB = 1u << 20;
  char* ws = (char*)d_ws;
  u16* XQ = (u16*)(ws + 0 * MB);
  u16* XK = (u16*)(ws + 8 * MB);
  u16* XV = (u16*)(ws + 16 * MB);
  u16* WQ = (u16*)(ws + 24 * MB);
  u16* WK = (u16*)(ws + 26 * MB);
  u16* WV = (u16*)(ws + 28 * MB);
  u16* WO = (u16*)(ws + 30 * MB);
  u16* Qb = (u16*)(ws + 32 * MB);
  u16* Kb = (u16*)(ws + 40 * MB);
  u16* Vt = (u16*)(ws + 48 * MB);
  u16* Ob = (u16*)(ws + 56 * MB);
  const bool merged = ws_size >= (size_t)80 * MB;
  u16* BiasE = (u16*)(ws + (merged ? 64 : 0) * MB);

  ConvArgs ca;
  ca.d[0] = {q_in, XQ, 4096 * 1024};
  ca.d[1] = {k_in, XK, 4096 * 1024};
  ca.d[2] = {v_in, XV, 4096 * 1024};
  ca.d[3] = {w_q, WQ, 1024 * 1024};
  ca.d[4] = {w_k, WK, 1024 * 1024};
  ca.d[5] = {w_v, WV, 1024 * 1024};
  ca.d[6] = {w_o, WO, 1024 * 1024};
  k_prep<<<dim3(2048, merged ? 8 : 7), 256, 0, stream>>>(ca, attn_bias, mask,
                                                         BiasE);

  const float QSCALE = 0.125f * 1.44269504f;
  Gemm3 g3;
  g3.d[0] = {XQ, WQ, b_q, (void*)Qb, 0, QSCALE};
  g3.d[1] = {XK, WK, b_k, (void*)Kb, 0, 1.0f};
  g3.d[2] = {XV, WV, b_v, (void*)Vt, 1, 1.0f};
  k_gemm_qkv<<<dim3(8, 32, 3), 256, 0, stream>>>(g3);

  if (!merged) k_biasprep<<<2048, 256, 0, stream>>>(attn_bias, mask, BiasE);

  k_attn<<<512, 256, 0, stream>>>(Qb, Kb, Vt, BiasE, Ob);

  k_gemm_o<<<dim3(8, 64), 256, 0, stream>>>(Ob, WO, b_o, (float*)d_out);
}